// Round 22
// baseline (657.641 us; speedup 1.0000x reference)
//
#include <hip/hip_runtime.h>

typedef unsigned short u16;
typedef unsigned int u32;
typedef __bf16 bf16x8 __attribute__((ext_vector_type(8)));
typedef float f32x4 __attribute__((ext_vector_type(4)));

#define B_SZ   4096
#define H_NUM  32
#define F_DIM  1024
#define NTOT   (H_NUM * F_DIM)   // 32768
#define N_CAT  8
#define CAT_D  16
#define N_CONT 24
#define LN_EPS 1e-5f
#define NSTRIP 128               // 256-col strips in the 256^2 GEMM

__device__ __forceinline__ u16 f2bf(float f) {
    unsigned int u = __builtin_bit_cast(unsigned int, f);
    unsigned int r = (u + 0x7FFFu + ((u >> 16) & 1u)) >> 16;
    return (u16)r;
}

__device__ __forceinline__ float bf2f(u16 v) {
    unsigned int u = ((unsigned int)v) << 16;
    return __builtin_bit_cast(float, u);
}

__device__ __forceinline__ float bflo(u32 v) { return bf2f((u16)(v & 0xffffu)); }
__device__ __forceinline__ float bfhi(u32 v) { return bf2f((u16)(v >> 16)); }

__device__ __forceinline__ void gl2lds16(const void* g, void* l) {
    __builtin_amdgcn_global_load_lds(
        (const __attribute__((address_space(1))) void*)g,
        (__attribute__((address_space(3))) void*)l,
        16, 0, 0);
}

__device__ __forceinline__ float wave_sum(float v) {
#pragma unroll
    for (int o = 32; o; o >>= 1) v += __shfl_xor(v, o);
    return v;
}

// ---------------- z f32 -> bf16 ----------------
__global__ __launch_bounds__(256) void zconv(const float* __restrict__ z,
                                             u16* __restrict__ zb) {
    int i = blockIdx.x * 256 + threadIdx.x;      // one float4 per thread
    float4 v = ((const float4*)z)[i];
    ushort4 o;
    o.x = f2bf(v.x); o.y = f2bf(v.y); o.z = f2bf(v.z); o.w = f2bf(v.w);
    ((ushort4*)zb)[i] = o;
}

// ---------------- pack lnw/lnb interleaved bf16 + Wcont bf16 ----------------
__global__ __launch_bounds__(256) void packln(const float* __restrict__ lnw,
                                              const float* __restrict__ lnb,
                                              const float* __restrict__ wcont,
                                              uint4* __restrict__ lnwb,
                                              ushort4* __restrict__ wc16) {
    int idx = blockIdx.x * 256 + threadIdx.x;
    if (idx < NTOT / 4) {
        float4 w = ((const float4*)lnw)[idx];
        float4 b = ((const float4*)lnb)[idx];
        uint4 o;
        o.x = (u32)f2bf(w.x) | ((u32)f2bf(w.y) << 16);
        o.y = (u32)f2bf(w.z) | ((u32)f2bf(w.w) << 16);
        o.z = (u32)f2bf(b.x) | ((u32)f2bf(b.y) << 16);
        o.w = (u32)f2bf(b.z) | ((u32)f2bf(b.w) << 16);
        lnwb[idx] = o;
    } else if (idx < NTOT / 4 + N_CONT * F_DIM / 4) {
        int j = idx - NTOT / 4;
        float4 v = ((const float4*)wcont)[j];
        ushort4 o;
        o.x = f2bf(v.x); o.y = f2bf(v.y); o.z = f2bf(v.z); o.w = f2bf(v.w);
        wc16[j] = o;
    }
}

// ---------------- W_proj [h][f][d] f32 -> Wt [h][d][f] bf16 ----------------
__global__ __launch_bounds__(256) void transpose_w(const float* __restrict__ W,
                                                   u16* __restrict__ Wt) {
    __shared__ u16 tile[64][72];
    const int h = blockIdx.z;
    const int f0 = blockIdx.x * 64;
    const int d0 = blockIdx.y * 64;
    const float* Wh = W + (size_t)h * F_DIM * F_DIM;
    u16* Wth = Wt + (size_t)h * F_DIM * F_DIM;
    const int t = threadIdx.x;

#pragma unroll
    for (int i = 0; i < 4; ++i) {
        int idx = i * 256 + t;        // 0..1023
        int fr = idx >> 4;            // 0..63
        int c4 = idx & 15;            // 0..15
        float4 v = *(const float4*)(Wh + (size_t)(f0 + fr) * F_DIM + d0 + c4 * 4);
        tile[fr][c4 * 4 + 0] = f2bf(v.x);
        tile[fr][c4 * 4 + 1] = f2bf(v.y);
        tile[fr][c4 * 4 + 2] = f2bf(v.z);
        tile[fr][c4 * 4 + 3] = f2bf(v.w);
    }
    __syncthreads();
#pragma unroll
    for (int i = 0; i < 2; ++i) {
        int idx = i * 256 + t;        // 0..511
        int dr = idx >> 3;            // 0..63
        int c8 = idx & 7;             // 0..7
        __attribute__((aligned(16))) u16 tmp[8];
#pragma unroll
        for (int j = 0; j < 8; ++j) tmp[j] = tile[c8 * 8 + j][dr];
        *(uint4*)(Wth + (size_t)(d0 + dr) * F_DIM + f0 + c8 * 8) = *(const uint4*)tmp;
    }
}

// ---------------- GEMM 256^2, 8 waves, 8-phase counted-vmcnt schedule (T3+T4) ----------------
// (R19-verified best: ~325us, MfmaUtil ~38%, 0 bank conflicts)
template <int BF>
__global__ __launch_bounds__(512, 2) void gemm256(const u16* __restrict__ A,
                                                  const u16* __restrict__ Bt,
                                                  const float* __restrict__ bproj,
                                                  u16* __restrict__ lat16,
                                                  float* __restrict__ latf,
                                                  float* __restrict__ psum,
                                                  float* __restrict__ psumsq) {
    extern __shared__ u16 dynlds[];
    const int t = threadIdx.x;
    const int wid = t >> 6;            // 0..7
    const int lane = t & 63;
    const int l16 = lane & 15;
    const int lk = lane >> 4;          // 0..3
    const int wm = wid >> 2;           // 0..1  (A half / 128-row block)
    const int wn = wid & 3;            // 0..3  (64-col block)

    const int wg = blockIdx.x;
    const int xcd = wg & 7;
    const int local = wg >> 3;         // 0..255
    const int m0 = (local & 15) * 256;
    const int n0 = ((xcd << 4) + (local >> 4)) * 256;

    f32x4 acc[8][4];
    const f32x4 zero = {0.f, 0.f, 0.f, 0.f};
#pragma unroll
    for (int m = 0; m < 8; ++m)
#pragma unroll
        for (int n = 0; n < 4; ++n) acc[m][n] = zero;

    // stage half-tile p of K-tile ktn into buffer bn (2 gload_lds per thread)
    auto stage = [&](int p, int ktn, int bn) {
        const char* srcbase = (p < 2) ? (const char*)A : (const char*)Bt;
        const int rowbase = (p < 2) ? (m0 + p * 128) : (n0 + (p - 2) * 128);
        u16* ldsbase = dynlds + bn * 32768 + (p >> 1) * 16384 + (p & 1) * 8192;
#pragma unroll
        for (int i = 0; i < 2; ++i) {
            int oo = i * 8192 + t * 16;                  // byte off in 16KB half
            int oos = oo ^ (((oo >> 7) & 7) << 4);       // pre-swizzled source
            int row = oo >> 7;
            int colb = oos & 127;
            gl2lds16(srcbase + (size_t)(rowbase + row) * 2048 + ktn * 128 + colb,
                     ldsbase + i * 4096 + (wid << 9));   // wave-uniform dest (u16 units)
        }
    };

    // prologue: kt0 complete + kt1's B halves (6 half-tiles, 12 loads/wave)
    stage(0, 0, 0); stage(1, 0, 0); stage(2, 0, 0); stage(3, 0, 0);
    stage(2, 1, 1); stage(3, 1, 1);
    asm volatile("s_waitcnt vmcnt(4)" ::: "memory");   // kt0's 4 halves landed
    asm volatile("s_barrier" ::: "memory");

    const int swz = (l16 & 7) << 4;                      // read-side XOR (bytes)
    for (int kt = 0; kt < 16; ++kt) {
        const int buf = kt & 1;
        const char* aB = (const char*)(dynlds + buf * 32768 + wm * 8192);
        const char* bB = (const char*)(dynlds + buf * 32768 + 16384 + (wn >> 1) * 8192);

        bf16x8 bfr[4][2];
#pragma unroll
        for (int p = 0; p < 4; ++p) {
            if (p == 0) {
#pragma unroll
                for (int nr = 0; nr < 4; ++nr)
#pragma unroll
                    for (int kk = 0; kk < 2; ++kk)
                        bfr[nr][kk] = *(const bf16x8*)(bB +
                            ((wn & 1) * 64 + nr * 16 + l16) * 128 +
                            ((kk * 64 + lk * 16) ^ swz));
            }
            bf16x8 afr[2][2];
#pragma unroll
            for (int mr = 0; mr < 2; ++mr)
#pragma unroll
                for (int kk = 0; kk < 2; ++kk)
                    afr[mr][kk] = *(const bf16x8*)(aB +
                        (p * 32 + mr * 16 + l16) * 128 +
                        ((kk * 64 + lk * 16) ^ swz));

            // stage exactly one half-tile this phase (dead-target proven)
            if (p == 0 && kt + 1 < 16) stage(0, kt + 1, buf ^ 1);
            if (p == 1 && kt + 1 < 16) stage(1, kt + 1, buf ^ 1);
            if (p == 2 && kt + 2 < 16) stage(2, kt + 2, buf);
            if (p == 3 && kt + 2 < 16) stage(3, kt + 2, buf);

            asm volatile("s_barrier" ::: "memory");      // lockstep before MFMA
            __builtin_amdgcn_s_setprio(1);
#pragma unroll
            for (int kk = 0; kk < 2; ++kk)
#pragma unroll
                for (int mr = 0; mr < 2; ++mr)
#pragma unroll
                    for (int nr = 0; nr < 4; ++nr)
                        acc[p * 2 + mr][nr] = __builtin_amdgcn_mfma_f32_16x16x32_bf16(
                            afr[mr][kk], bfr[nr][kk], acc[p * 2 + mr][nr], 0, 0, 0);
            __builtin_amdgcn_s_setprio(0);
            if (p == 3) {
                if (kt < 14)       asm volatile("s_waitcnt vmcnt(4)" ::: "memory");
                else if (kt == 14) asm volatile("s_waitcnt vmcnt(0)" ::: "memory");
            }
            asm volatile("s_barrier" ::: "memory");      // phase end
        }
    }

    // ---- epilogue: bf16 latent store + LN partials (reuse dead LDS) ----
    float bias[4];
#pragma unroll
    for (int nr = 0; nr < 4; ++nr) bias[nr] = bproj[n0 + wn * 64 + nr * 16 + l16];

    float sm[8][4], s2[8][4];
#pragma unroll
    for (int mr = 0; mr < 8; ++mr)
#pragma unroll
        for (int j = 0; j < 4; ++j) { sm[mr][j] = 0.f; s2[mr][j] = 0.f; }

#pragma unroll
    for (int mr = 0; mr < 8; ++mr) {
#pragma unroll
        for (int j = 0; j < 4; ++j) {
            const int rowg = m0 + wm * 128 + mr * 16 + lk * 4 + j;
            size_t off = (size_t)rowg * NTOT + n0 + wn * 64 + l16;
#pragma unroll
            for (int nr = 0; nr < 4; ++nr) {
                float v = acc[mr][nr][j] + bias[nr];
                if (BF) lat16[off + nr * 16] = f2bf(v);
                else    latf[off + nr * 16] = v;
                sm[mr][j] += v;
                s2[mr][j] += v * v;
            }
        }
    }
#pragma unroll
    for (int o = 1; o < 16; o <<= 1) {
#pragma unroll
        for (int mr = 0; mr < 8; ++mr)
#pragma unroll
            for (int j = 0; j < 4; ++j) {
                sm[mr][j] += __shfl_xor(sm[mr][j], o);
                s2[mr][j] += __shfl_xor(s2[mr][j], o);
            }
    }
    float* sredf = (float*)dynlds;            // [4][256]  (aliases dead buffers)
    float* s2f   = sredf + 1024;              // [4][256]
    __syncthreads();
    if (l16 == 0) {
#pragma unroll
        for (int mr = 0; mr < 8; ++mr)
#pragma unroll
            for (int j = 0; j < 4; ++j) {
                int r = wm * 128 + mr * 16 + lk * 4 + j;
                sredf[wn * 256 + r] = sm[mr][j];
                s2f[wn * 256 + r] = s2[mr][j];
            }
    }
    __syncthreads();
    if (t < 256) {
        const int strip = n0 >> 8;
        float S = sredf[t] + sredf[256 + t] + sredf[512 + t] + sredf[768 + t];
        float S2 = s2f[t] + s2f[256 + t] + s2f[512 + t] + s2f[768 + t];
        psum[(size_t)strip * B_SZ + m0 + t] = S;
        psumsq[(size_t)strip * B_SZ + m0 + t] = S2;
    }
}

// ---------------- finalize LN stats from partials (psum layout [strip][b]) ----------------
__global__ __launch_bounds__(256) void ln_finalize(const float* __restrict__ psum,
                                                   const float* __restrict__ psumsq,
                                                   float* __restrict__ murs) {
    const int t = threadIdx.x;
    const int b0 = blockIdx.x * 64;
    const int tb = t & 63;            // which b
    const int tg = t >> 6;            // strip group 0..3
    float s = 0.f, s2 = 0.f;
    for (int sidx = tg; sidx < NSTRIP; sidx += 4) {
        s += psum[(size_t)sidx * B_SZ + b0 + tb];
        s2 += psumsq[(size_t)sidx * B_SZ + b0 + tb];
    }
    __shared__ float r1[4][64], r2[4][64];
    r1[tg][tb] = s;
    r2[tg][tb] = s2;
    __syncthreads();
    if (t < 64) {
        float S = r1[0][t] + r1[1][t] + r1[2][t] + r1[3][t];
        float S2 = r2[0][t] + r2[1][t] + r2[2][t] + r2[3][t];
        float m = S / (float)NTOT;
        float var = S2 / (float)NTOT - m * m;
        murs[b0 + t] = m;
        murs[B_SZ + b0 + t] = rsqrtf(var + LN_EPS);
    }
}

// ---------------- cont heads: pure streaming, 4 blocks per b (6 heads each) ----------------
// Finer decomposition than R19's 3x8: shorter per-thread serial chain, +33% TLP.
template <int BF>
__global__ __launch_bounds__(256) void contK4(const void* __restrict__ latin_,
                                              float* __restrict__ latout,
                                              const float* __restrict__ murs,
                                              const uint4* __restrict__ lnwb,
                                              const ushort4* __restrict__ wc16,
                                              const float* __restrict__ bcont,
                                              float* __restrict__ pcont) {
    const int g = blockIdx.x;                 // 0..3 (fastest: 4 blocks share b)
    const int b = blockIdx.y;
    const int t = threadIdx.x;
    const int lane = t & 63;
    const int w4 = t >> 6;
    const float mu = murs[b];
    const float rs = murs[B_SZ + b];
    const ushort4* lin16 = (const ushort4*)((const u16*)latin_ + (size_t)b * NTOT);
    const float4*  linf  = (const float4*)((const float*)latin_ + (size_t)b * NTOT);
    float4* lout4 = (float4*)(latout + (size_t)b * NTOT);

    __shared__ float red[6][4];

    float cp6[6];
#pragma unroll
    for (int j = 0; j < 6; ++j) {
        const int k = N_CAT + g * 6 + j;
        const int i = (k << 8) + t;
        float4 x;
        if (BF) {
            ushort4 xv = lin16[i];
            x.x = bf2f(xv.x); x.y = bf2f(xv.y); x.z = bf2f(xv.z); x.w = bf2f(xv.w);
        } else {
            x = linf[i];
        }
        uint4 wb = lnwb[i];
        ushort4 wv = wc16[((g * 6 + j) << 8) + t];
        float4 yo;
        yo.x = fmaxf(0.f, (x.x - mu) * rs * bflo(wb.x) + bflo(wb.z));
        yo.y = fmaxf(0.f, (x.y - mu) * rs * bfhi(wb.x) + bfhi(wb.z));
        yo.z = fmaxf(0.f, (x.z - mu) * rs * bflo(wb.y) + bflo(wb.w));
        yo.w = fmaxf(0.f, (x.w - mu) * rs * bfhi(wb.y) + bfhi(wb.w));
        lout4[i] = yo;
        cp6[j] = yo.x * bf2f(wv.x) + yo.y * bf2f(wv.y) +
                 yo.z * bf2f(wv.z) + yo.w * bf2f(wv.w);
    }
#pragma unroll
    for (int j = 0; j < 6; ++j) {
        float v = wave_sum(cp6[j]);
        if (lane == 0) red[j][w4] = v;
    }
    __syncthreads();
    if (t < 6) {
        const int ci = g * 6 + t;
        pcont[(size_t)b * N_CONT + ci] =
            red[t][0] + red[t][1] + red[t][2] + red[t][3] + bcont[ci];
    }
}

// ---------------- cat heads: 2 blocks per b (4 heads each) ----------------
// Halves the serial GEMV chain per block; LDS 18.4 -> 9.2 KB.
template <int BF>
__global__ __launch_bounds__(256) void catK2(const void* __restrict__ latin_,
                                             float* __restrict__ latout,
                                             const float* __restrict__ murs,
                                             const uint4* __restrict__ lnwb,
                                             const float* __restrict__ Wcat,
                                             const float* __restrict__ bcat,
                                             float* __restrict__ pcat) {
    const int half = blockIdx.x;              // 0..1
    const int b = blockIdx.y;
    const int hb = half * 4;                  // head base
    const int t = threadIdx.x;
    const int lane = t & 63;
    const int w4 = t >> 6;                    // wave 0..3
    const float mu = murs[b];
    const float rs = murs[B_SZ + b];
    const ushort4* lin16 = (const ushort4*)((const u16*)latin_ + (size_t)b * NTOT);
    const float4*  linf  = (const float4*)((const float*)latin_ + (size_t)b * NTOT);
    float4* lout4 = (float4*)(latout + (size_t)b * NTOT);

    __shared__ ushort4 sy16[4 * 256];         // 4 heads' y, bf16 (8 KB)
    __shared__ float4 cred4[4][4][4];         // [wave][k][cq] partials (1 KB)

    // ---- phase 1: normalize, store, stage y (fully unrolled, no barriers) ----
#pragma unroll
    for (int k = 0; k < 4; ++k) {
        const int i = ((hb + k) << 8) + t;
        float4 x;
        if (BF) {
            ushort4 xv = lin16[i];
            x.x = bf2f(xv.x); x.y = bf2f(xv.y); x.z = bf2f(xv.z); x.w = bf2f(xv.w);
        } else {
            x = linf[i];
        }
        uint4 wb = lnwb[i];
        float4 yo;
        yo.x = fmaxf(0.f, (x.x - mu) * rs * bflo(wb.x) + bflo(wb.z));
        yo.y = fmaxf(0.f, (x.y - mu) * rs * bfhi(wb.x) + bfhi(wb.z));
        yo.z = fmaxf(0.f, (x.z - mu) * rs * bflo(wb.y) + bflo(wb.w));
        yo.w = fmaxf(0.f, (x.w - mu) * rs * bfhi(wb.y) + bfhi(wb.w));
        lout4[i] = yo;
        ushort4 ys;
        ys.x = f2bf(yo.x); ys.y = f2bf(yo.y); ys.z = f2bf(yo.z); ys.w = f2bf(yo.w);
        sy16[(k << 8) + t] = ys;               // own slot, no race
    }
    __syncthreads();

    // ---- phase 2: 4 GEMVs from LDS, float4 Wcat (cq = t&3, fg = t>>2) ----
    const int cq = t & 3;
    const int fg = t >> 2;                    // 0..63
    for (int k = 0; k < 4; ++k) {
        const float4* Wc4 = (const float4*)(Wcat + (size_t)(hb + k) * F_DIM * CAT_D);
        float4 a4 = {0.f, 0.f, 0.f, 0.f};
#pragma unroll
        for (int jq = 0; jq < 4; ++jq) {
            ushort4 yv = sy16[(k << 8) + fg * 4 + jq];
            float ys[4] = {bf2f(yv.x), bf2f(yv.y), bf2f(yv.z), bf2f(yv.w)};
#pragma unroll
            for (int r = 0; r < 4; ++r) {
                int f = fg * 16 + jq * 4 + r;
                float4 wv = Wc4[f * 4 + cq];
                a4.x += ys[r] * wv.x;
                a4.y += ys[r] * wv.y;
                a4.z += ys[r] * wv.z;
                a4.w += ys[r] * wv.w;
            }
        }
#pragma unroll
        for (int o = 4; o < 64; o <<= 1) {
            a4.x += __shfl_xor(a4.x, o);
            a4.y += __shfl_xor(a4.y, o);
            a4.z += __shfl_xor(a4.z, o);
            a4.w += __shfl_xor(a4.w, o);
        }
        if (lane < 4) cred4[w4][k][lane] = a4;   // lane == cq for lanes 0..3
    }
    __syncthreads();

    // ---- phase 3: softmax (4 heads, t<64: k = t>>4, c = t&15) ----
    if (t < 64) {
        const int k = t >> 4, c = t & 15;
        const int h = hb + k;
        float lg = bcat[h * CAT_D + c];
#pragma unroll
        for (int w = 0; w < 4; ++w)
            lg += ((const float*)cred4[w][k])[c];
        float mx = lg;
#pragma unroll
        for (int o = 8; o; o >>= 1) mx = fmaxf(mx, __shfl_xor(mx, o, 16));
        float e = __expf(lg - mx);
        float sm2 = e;
#pragma unroll
        for (int o = 8; o; o >>= 1) sm2 += __shfl_xor(sm2, o, 16);
        pcat[(size_t)b * (N_CAT * CAT_D) + h * CAT_D + c] = e / sm2;
    }
}

extern "C" void kernel_launch(void* const* d_in, const int* in_sizes, int n_in,
                              void* d_out, int out_size, void* d_ws, size_t ws_size,
                              hipStream_t stream) {
    const float* z     = (const float*)d_in[0];
    // d_in[1] = edge (unused by reference computation)
    const float* Wp    = (const float*)d_in[2];
    const float* bp    = (const float*)d_in[3];
    const float* lnw   = (const float*)d_in[4];
    const float* lnb   = (const float*)d_in[5];
    const float* Wcat  = (const float*)d_in[6];
    const float* bcat  = (const float*)d_in[7];
    const float* Wcont = (const float*)d_in[8];
    const float* bcont = (const float*)d_in[9];

    float* out    = (float*)d_out;
    float* pcat   = out;                                   // [4096, 8, 16]
    float* pcont  = out + (size_t)B_SZ * N_CAT * CAT_D;    // [4096, 24, 1]
    float* latent = pcont + (size_t)B_SZ * N_CONT;         // [4096, 32, 1024]

    u16* zb     = (u16*)d_ws;                              // 8 MB
    u16* Wt     = zb + (size_t)B_SZ * F_DIM;               // 64 MB
    float* murs = (float*)(Wt + (size_t)NTOT * F_DIM);     // 32 KB
    float* psum   = murs + 2 * B_SZ;                       // [128][4096] 2 MB
    float* psumsq = psum + (size_t)B_SZ * NSTRIP;          // 2 MB
    uint4* lnwb = (uint4*)(psumsq + (size_t)B_SZ * NSTRIP);        // 128 KB
    ushort4* wc16 = (ushort4*)(lnwb + NTOT / 4);                   // 48 KB
    u16* lat16  = (u16*)(wc16 + N_CONT * F_DIM / 4);       // 256 MB (optional)

    const size_t need = (size_t)((char*)(lat16 + (size_t)B_SZ * NTOT) - (char*)d_ws);
    const bool usebf = ws_size >= need;

    const int LDSB = 131072;
    zconv<<<dim3(B_SZ * F_DIM / 1024), 256, 0, stream>>>(z, zb);
    packln<<<dim3((NTOT / 4 + N_CONT * F_DIM / 4 + 255) / 256), 256, 0, stream>>>(
        lnw, lnb, Wcont, lnwb, wc16);
    transpose_w<<<dim3(16, 16, 32), 256, 0, stream>>>(Wp, Wt);
    if (usebf) {
        (void)hipFuncSetAttribute((const void*)gemm256<1>,
                                  hipFuncAttributeMaxDynamicSharedMemorySize, LDSB);
        gemm256<1><<<dim3(2048), 512, LDSB, stream>>>(zb, Wt, bp, lat16, nullptr,
                                                      psum, psumsq);
        ln_finalize<<<dim3(B_SZ / 64), 256, 0, stream>>>(psum, psumsq, murs);
        contK4<1><<<dim3(4, B_SZ), 256, 0, stream>>>(lat16, latent, murs, lnwb, wc16,
                                                     bcont, pcont);
        catK2<1><<<dim3(2, B_SZ), 256, 0, stream>>>(lat16, latent, murs, lnwb,
                                                    Wcat, bcat, pcat);
    } else {
        (void)hipFuncSetAttribute((const void*)gemm256<0>,
                                  hipFuncAttributeMaxDynamicSharedMemorySize, LDSB);
        gemm256<0><<<dim3(2048), 512, LDSB, stream>>>(zb, Wt, bp, nullptr, latent,
                                                      psum, psumsq);
        ln_finalize<<<dim3(B_SZ / 64), 256, 0, stream>>>(psum, psumsq, murs);
        contK4<0><<<dim3(4, B_SZ), 256, 0, stream>>>(latent, latent, murs, lnwb, wc16,
                                                     bcont, pcont);
        catK2<0><<<dim3(2, B_SZ), 256, 0, stream>>>(latent, latent, murs, lnwb,
                                                    Wcat, bcat, pcat);
    }
}

// Round 23
// 649.118 us; speedup vs baseline: 1.0131x; 1.0131x over previous
//
#include <hip/hip_runtime.h>

typedef unsigned short u16;
typedef unsigned int u32;
typedef __bf16 bf16x8 __attribute__((ext_vector_type(8)));
typedef float f32x4 __attribute__((ext_vector_type(4)));

#define B_SZ   4096
#define H_NUM  32
#define F_DIM  1024
#define NTOT   (H_NUM * F_DIM)   // 32768
#define N_CAT  8
#define CAT_D  16
#define N_CONT 24
#define LN_EPS 1e-5f
#define NSTRIP 128               // 256-col strips in the 256^2 GEMM

__device__ __forceinline__ u16 f2bf(float f) {
    unsigned int u = __builtin_bit_cast(unsigned int, f);
    unsigned int r = (u + 0x7FFFu + ((u >> 16) & 1u)) >> 16;
    return (u16)r;
}

__device__ __forceinline__ float bf2f(u16 v) {
    unsigned int u = ((unsigned int)v) << 16;
    return __builtin_bit_cast(float, u);
}

__device__ __forceinline__ float bflo(u32 v) { return bf2f((u16)(v & 0xffffu)); }
__device__ __forceinline__ float bfhi(u32 v) { return bf2f((u16)(v >> 16)); }

__device__ __forceinline__ void gl2lds16(const void* g, void* l) {
    __builtin_amdgcn_global_load_lds(
        (const __attribute__((address_space(1))) void*)g,
        (__attribute__((address_space(3))) void*)l,
        16, 0, 0);
}

__device__ __forceinline__ float wave_sum(float v) {
#pragma unroll
    for (int o = 32; o; o >>= 1) v += __shfl_xor(v, o);
    return v;
}

// ---------------- z f32 -> bf16 ----------------
__global__ __launch_bounds__(256) void zconv(const float* __restrict__ z,
                                             u16* __restrict__ zb) {
    int i = blockIdx.x * 256 + threadIdx.x;      // one float4 per thread
    float4 v = ((const float4*)z)[i];
    ushort4 o;
    o.x = f2bf(v.x); o.y = f2bf(v.y); o.z = f2bf(v.z); o.w = f2bf(v.w);
    ((ushort4*)zb)[i] = o;
}

// ---------------- pack lnw/lnb interleaved bf16 + Wcont bf16 ----------------
__global__ __launch_bounds__(256) void packln(const float* __restrict__ lnw,
                                              const float* __restrict__ lnb,
                                              const float* __restrict__ wcont,
                                              uint4* __restrict__ lnwb,
                                              ushort4* __restrict__ wc16) {
    int idx = blockIdx.x * 256 + threadIdx.x;
    if (idx < NTOT / 4) {
        float4 w = ((const float4*)lnw)[idx];
        float4 b = ((const float4*)lnb)[idx];
        uint4 o;
        o.x = (u32)f2bf(w.x) | ((u32)f2bf(w.y) << 16);
        o.y = (u32)f2bf(w.z) | ((u32)f2bf(w.w) << 16);
        o.z = (u32)f2bf(b.x) | ((u32)f2bf(b.y) << 16);
        o.w = (u32)f2bf(b.z) | ((u32)f2bf(b.w) << 16);
        lnwb[idx] = o;
    } else if (idx < NTOT / 4 + N_CONT * F_DIM / 4) {
        int j = idx - NTOT / 4;
        float4 v = ((const float4*)wcont)[j];
        ushort4 o;
        o.x = f2bf(v.x); o.y = f2bf(v.y); o.z = f2bf(v.z); o.w = f2bf(v.w);
        wc16[j] = o;
    }
}

// ---------------- W_proj [h][f][d] f32 -> Wt [h][d][f] bf16 ----------------
__global__ __launch_bounds__(256) void transpose_w(const float* __restrict__ W,
                                                   u16* __restrict__ Wt) {
    __shared__ u16 tile[64][72];
    const int h = blockIdx.z;
    const int f0 = blockIdx.x * 64;
    const int d0 = blockIdx.y * 64;
    const float* Wh = W + (size_t)h * F_DIM * F_DIM;
    u16* Wth = Wt + (size_t)h * F_DIM * F_DIM;
    const int t = threadIdx.x;

#pragma unroll
    for (int i = 0; i < 4; ++i) {
        int idx = i * 256 + t;        // 0..1023
        int fr = idx >> 4;            // 0..63
        int c4 = idx & 15;            // 0..15
        float4 v = *(const float4*)(Wh + (size_t)(f0 + fr) * F_DIM + d0 + c4 * 4);
        tile[fr][c4 * 4 + 0] = f2bf(v.x);
        tile[fr][c4 * 4 + 1] = f2bf(v.y);
        tile[fr][c4 * 4 + 2] = f2bf(v.z);
        tile[fr][c4 * 4 + 3] = f2bf(v.w);
    }
    __syncthreads();
#pragma unroll
    for (int i = 0; i < 2; ++i) {
        int idx = i * 256 + t;        // 0..511
        int dr = idx >> 3;            // 0..63
        int c8 = idx & 7;             // 0..7
        __attribute__((aligned(16))) u16 tmp[8];
#pragma unroll
        for (int j = 0; j < 8; ++j) tmp[j] = tile[c8 * 8 + j][dr];
        *(uint4*)(Wth + (size_t)(d0 + dr) * F_DIM + f0 + c8 * 8) = *(const uint4*)tmp;
    }
}

// ---------------- GEMM 256^2, 8 waves, 8-phase counted-vmcnt, 1 barrier/phase ----------------
// R22 change: removed the pre-MFMA barrier (kept phase-end only, 64 vs 128/block).
// Safety: with phase-end barriers, waves diverge by at most one phase-window.
// ds_reads target buf regions written >=2 barriers ago; stage targets are dead:
// (kt+1).A halves last read during kt-1 (>=1 barrier back), (kt+2).B halves read
// only in phase 0 of kt and stage(2/3) issue after the phase-1-end barrier.
// vmcnt(4) gate unchanged at p3 before the phase-end barrier.
template <int BF>
__global__ __launch_bounds__(512, 2) void gemm256(const u16* __restrict__ A,
                                                  const u16* __restrict__ Bt,
                                                  const float* __restrict__ bproj,
                                                  u16* __restrict__ lat16,
                                                  float* __restrict__ latf,
                                                  float* __restrict__ psum,
                                                  float* __restrict__ psumsq) {
    extern __shared__ u16 dynlds[];
    const int t = threadIdx.x;
    const int wid = t >> 6;            // 0..7
    const int lane = t & 63;
    const int l16 = lane & 15;
    const int lk = lane >> 4;          // 0..3
    const int wm = wid >> 2;           // 0..1  (A half / 128-row block)
    const int wn = wid & 3;            // 0..3  (64-col block)

    const int wg = blockIdx.x;
    const int xcd = wg & 7;
    const int local = wg >> 3;         // 0..255
    const int m0 = (local & 15) * 256;
    const int n0 = ((xcd << 4) + (local >> 4)) * 256;

    f32x4 acc[8][4];
    const f32x4 zero = {0.f, 0.f, 0.f, 0.f};
#pragma unroll
    for (int m = 0; m < 8; ++m)
#pragma unroll
        for (int n = 0; n < 4; ++n) acc[m][n] = zero;

    // stage half-tile p of K-tile ktn into buffer bn (2 gload_lds per thread)
    auto stage = [&](int p, int ktn, int bn) {
        const char* srcbase = (p < 2) ? (const char*)A : (const char*)Bt;
        const int rowbase = (p < 2) ? (m0 + p * 128) : (n0 + (p - 2) * 128);
        u16* ldsbase = dynlds + bn * 32768 + (p >> 1) * 16384 + (p & 1) * 8192;
#pragma unroll
        for (int i = 0; i < 2; ++i) {
            int oo = i * 8192 + t * 16;                  // byte off in 16KB half
            int oos = oo ^ (((oo >> 7) & 7) << 4);       // pre-swizzled source
            int row = oo >> 7;
            int colb = oos & 127;
            gl2lds16(srcbase + (size_t)(rowbase + row) * 2048 + ktn * 128 + colb,
                     ldsbase + i * 4096 + (wid << 9));   // wave-uniform dest (u16 units)
        }
    };

    // prologue: kt0 complete + kt1's B halves (6 half-tiles, 12 loads/wave)
    stage(0, 0, 0); stage(1, 0, 0); stage(2, 0, 0); stage(3, 0, 0);
    stage(2, 1, 1); stage(3, 1, 1);
    asm volatile("s_waitcnt vmcnt(4)" ::: "memory");   // kt0's 4 halves landed
    asm volatile("s_barrier" ::: "memory");

    const int swz = (l16 & 7) << 4;                      // read-side XOR (bytes)
    for (int kt = 0; kt < 16; ++kt) {
        const int buf = kt & 1;
        const char* aB = (const char*)(dynlds + buf * 32768 + wm * 8192);
        const char* bB = (const char*)(dynlds + buf * 32768 + 16384 + (wn >> 1) * 8192);

        bf16x8 bfr[4][2];
#pragma unroll
        for (int p = 0; p < 4; ++p) {
            if (p == 0) {
#pragma unroll
                for (int nr = 0; nr < 4; ++nr)
#pragma unroll
                    for (int kk = 0; kk < 2; ++kk)
                        bfr[nr][kk] = *(const bf16x8*)(bB +
                            ((wn & 1) * 64 + nr * 16 + l16) * 128 +
                            ((kk * 64 + lk * 16) ^ swz));
            }
            bf16x8 afr[2][2];
#pragma unroll
            for (int mr = 0; mr < 2; ++mr)
#pragma unroll
                for (int kk = 0; kk < 2; ++kk)
                    afr[mr][kk] = *(const bf16x8*)(aB +
                        (p * 32 + mr * 16 + l16) * 128 +
                        ((kk * 64 + lk * 16) ^ swz));

            // stage exactly one half-tile this phase (dead-target proven)
            if (p == 0 && kt + 1 < 16) stage(0, kt + 1, buf ^ 1);
            if (p == 1 && kt + 1 < 16) stage(1, kt + 1, buf ^ 1);
            if (p == 2 && kt + 2 < 16) stage(2, kt + 2, buf);
            if (p == 3 && kt + 2 < 16) stage(3, kt + 2, buf);

            __builtin_amdgcn_s_setprio(1);
#pragma unroll
            for (int kk = 0; kk < 2; ++kk)
#pragma unroll
                for (int mr = 0; mr < 2; ++mr)
#pragma unroll
                    for (int nr = 0; nr < 4; ++nr)
                        acc[p * 2 + mr][nr] = __builtin_amdgcn_mfma_f32_16x16x32_bf16(
                            afr[mr][kk], bfr[nr][kk], acc[p * 2 + mr][nr], 0, 0, 0);
            __builtin_amdgcn_s_setprio(0);
            if (p == 3) {
                if (kt < 14)       asm volatile("s_waitcnt vmcnt(4)" ::: "memory");
                else if (kt == 14) asm volatile("s_waitcnt vmcnt(0)" ::: "memory");
            }
            asm volatile("s_barrier" ::: "memory");      // phase end (only barrier)
        }
    }

    // ---- epilogue: bf16 latent store + LN partials (reuse dead LDS) ----
    float bias[4];
#pragma unroll
    for (int nr = 0; nr < 4; ++nr) bias[nr] = bproj[n0 + wn * 64 + nr * 16 + l16];

    float sm[8][4], s2[8][4];
#pragma unroll
    for (int mr = 0; mr < 8; ++mr)
#pragma unroll
        for (int j = 0; j < 4; ++j) { sm[mr][j] = 0.f; s2[mr][j] = 0.f; }

#pragma unroll
    for (int mr = 0; mr < 8; ++mr) {
#pragma unroll
        for (int j = 0; j < 4; ++j) {
            const int rowg = m0 + wm * 128 + mr * 16 + lk * 4 + j;
            size_t off = (size_t)rowg * NTOT + n0 + wn * 64 + l16;
#pragma unroll
            for (int nr = 0; nr < 4; ++nr) {
                float v = acc[mr][nr][j] + bias[nr];
                if (BF) lat16[off + nr * 16] = f2bf(v);
                else    latf[off + nr * 16] = v;
                sm[mr][j] += v;
                s2[mr][j] += v * v;
            }
        }
    }
#pragma unroll
    for (int o = 1; o < 16; o <<= 1) {
#pragma unroll
        for (int mr = 0; mr < 8; ++mr)
#pragma unroll
            for (int j = 0; j < 4; ++j) {
                sm[mr][j] += __shfl_xor(sm[mr][j], o);
                s2[mr][j] += __shfl_xor(s2[mr][j], o);
            }
    }
    float* sredf = (float*)dynlds;            // [4][256]  (aliases dead buffers)
    float* s2f   = sredf + 1024;              // [4][256]
    __syncthreads();
    if (l16 == 0) {
#pragma unroll
        for (int mr = 0; mr < 8; ++mr)
#pragma unroll
            for (int j = 0; j < 4; ++j) {
                int r = wm * 128 + mr * 16 + lk * 4 + j;
                sredf[wn * 256 + r] = sm[mr][j];
                s2f[wn * 256 + r] = s2[mr][j];
            }
    }
    __syncthreads();
    if (t < 256) {
        const int strip = n0 >> 8;
        float S = sredf[t] + sredf[256 + t] + sredf[512 + t] + sredf[768 + t];
        float S2 = s2f[t] + s2f[256 + t] + s2f[512 + t] + s2f[768 + t];
        psum[(size_t)strip * B_SZ + m0 + t] = S;
        psumsq[(size_t)strip * B_SZ + m0 + t] = S2;
    }
}

// ---------------- finalize LN stats from partials (psum layout [strip][b]) ----------------
__global__ __launch_bounds__(256) void ln_finalize(const float* __restrict__ psum,
                                                   const float* __restrict__ psumsq,
                                                   float* __restrict__ murs) {
    const int t = threadIdx.x;
    const int b0 = blockIdx.x * 64;
    const int tb = t & 63;            // which b
    const int tg = t >> 6;            // strip group 0..3
    float s = 0.f, s2 = 0.f;
    for (int sidx = tg; sidx < NSTRIP; sidx += 4) {
        s += psum[(size_t)sidx * B_SZ + b0 + tb];
        s2 += psumsq[(size_t)sidx * B_SZ + b0 + tb];
    }
    __shared__ float r1[4][64], r2[4][64];
    r1[tg][tb] = s;
    r2[tg][tb] = s2;
    __syncthreads();
    if (t < 64) {
        float S = r1[0][t] + r1[1][t] + r1[2][t] + r1[3][t];
        float S2 = r2[0][t] + r2[1][t] + r2[2][t] + r2[3][t];
        float m = S / (float)NTOT;
        float var = S2 / (float)NTOT - m * m;
        murs[b0 + t] = m;
        murs[B_SZ + b0 + t] = rsqrtf(var + LN_EPS);
    }
}

// ---------------- cont heads: pure streaming, zero barriers in stream (R21 best) ----------------
template <int BF>
__global__ __launch_bounds__(256) void contK(const void* __restrict__ latin_,
                                             float* __restrict__ latout,
                                             const float* __restrict__ murs,
                                             const uint4* __restrict__ lnwb,
                                             const ushort4* __restrict__ wc16,
                                             const float* __restrict__ bcont,
                                             float* __restrict__ pcont) {
    const int g = blockIdx.x;                 // 0..2 (fastest: 3 blocks share b)
    const int b = blockIdx.y;
    const int t = threadIdx.x;
    const int lane = t & 63;
    const int w4 = t >> 6;
    const float mu = murs[b];
    const float rs = murs[B_SZ + b];
    const ushort4* lin16 = (const ushort4*)((const u16*)latin_ + (size_t)b * NTOT);
    const float4*  linf  = (const float4*)((const float*)latin_ + (size_t)b * NTOT);
    float4* lout4 = (float4*)(latout + (size_t)b * NTOT);

    __shared__ float red[8][4];

    float cp8[8];
#pragma unroll
    for (int j = 0; j < 8; ++j) {
        const int k = N_CAT + g * 8 + j;
        const int i = (k << 8) + t;
        float4 x;
        if (BF) {
            ushort4 xv = lin16[i];
            x.x = bf2f(xv.x); x.y = bf2f(xv.y); x.z = bf2f(xv.z); x.w = bf2f(xv.w);
        } else {
            x = linf[i];
        }
        uint4 wb = lnwb[i];
        ushort4 wv = wc16[((g * 8 + j) << 8) + t];
        float4 yo;
        yo.x = fmaxf(0.f, (x.x - mu) * rs * bflo(wb.x) + bflo(wb.z));
        yo.y = fmaxf(0.f, (x.y - mu) * rs * bfhi(wb.x) + bfhi(wb.z));
        yo.z = fmaxf(0.f, (x.z - mu) * rs * bflo(wb.y) + bflo(wb.w));
        yo.w = fmaxf(0.f, (x.w - mu) * rs * bfhi(wb.y) + bfhi(wb.w));
        lout4[i] = yo;
        cp8[j] = yo.x * bf2f(wv.x) + yo.y * bf2f(wv.y) +
                 yo.z * bf2f(wv.z) + yo.w * bf2f(wv.w);
    }
#pragma unroll
    for (int j = 0; j < 8; ++j) {
        float v = wave_sum(cp8[j]);
        if (lane == 0) red[j][w4] = v;
    }
    __syncthreads();
    if (t < 8) {
        const int ci = g * 8 + t;
        pcont[(size_t)b * N_CONT + ci] =
            red[t][0] + red[t][1] + red[t][2] + red[t][3] + bcont[ci];
    }
}

// ---------------- cat heads: normalize + stage + GEMV + softmax, one block per b ----------------
template <int BF>
__global__ __launch_bounds__(256) void catK(const void* __restrict__ latin_,
                                            float* __restrict__ latout,
                                            const float* __restrict__ murs,
                                            const uint4* __restrict__ lnwb,
                                            const float* __restrict__ Wcat,
                                            const float* __restrict__ bcat,
                                            float* __restrict__ pcat) {
    const int b = blockIdx.x;
    const int t = threadIdx.x;
    const int lane = t & 63;
    const int w4 = t >> 6;                    // wave 0..3
    const float mu = murs[b];
    const float rs = murs[B_SZ + b];
    const ushort4* lin16 = (const ushort4*)((const u16*)latin_ + (size_t)b * NTOT);
    const float4*  linf  = (const float4*)((const float*)latin_ + (size_t)b * NTOT);
    float4* lout4 = (float4*)(latout + (size_t)b * NTOT);

    __shared__ ushort4 sy16[N_CAT * 256];     // 8 cat heads' y, bf16 (16 KB)
    __shared__ float4 cred4[4][N_CAT][4];     // [wave][h][cq] partials (2 KB)

    // ---- phase 1: normalize, store, stage y (fully unrolled, no barriers) ----
#pragma unroll
    for (int k = 0; k < N_CAT; ++k) {
        const int i = (k << 8) + t;
        float4 x;
        if (BF) {
            ushort4 xv = lin16[i];
            x.x = bf2f(xv.x); x.y = bf2f(xv.y); x.z = bf2f(xv.z); x.w = bf2f(xv.w);
        } else {
            x = linf[i];
        }
        uint4 wb = lnwb[i];
        float4 yo;
        yo.x = fmaxf(0.f, (x.x - mu) * rs * bflo(wb.x) + bflo(wb.z));
        yo.y = fmaxf(0.f, (x.y - mu) * rs * bfhi(wb.x) + bfhi(wb.z));
        yo.z = fmaxf(0.f, (x.z - mu) * rs * bflo(wb.y) + bflo(wb.w));
        yo.w = fmaxf(0.f, (x.w - mu) * rs * bfhi(wb.y) + bfhi(wb.w));
        lout4[i] = yo;
        ushort4 ys;
        ys.x = f2bf(yo.x); ys.y = f2bf(yo.y); ys.z = f2bf(yo.z); ys.w = f2bf(yo.w);
        sy16[i] = ys;                          // own slot, no race
    }
    __syncthreads();

    // ---- phase 2: cat GEMVs from LDS, float4 Wcat (cq = t&3, fg = t>>2) ----
    const int cq = t & 3;
    const int fg = t >> 2;                    // 0..63
    for (int k = 0; k < N_CAT; ++k) {
        const float4* Wc4 = (const float4*)(Wcat + (size_t)k * F_DIM * CAT_D);
        float4 a4 = {0.f, 0.f, 0.f, 0.f};
#pragma unroll
        for (int jq = 0; jq < 4; ++jq) {
            ushort4 yv = sy16[(k << 8) + fg * 4 + jq];
            float ys[4] = {bf2f(yv.x), bf2f(yv.y), bf2f(yv.z), bf2f(yv.w)};
#pragma unroll
            for (int r = 0; r < 4; ++r) {
                int f = fg * 16 + jq * 4 + r;
                float4 wv = Wc4[f * 4 + cq];
                a4.x += ys[r] * wv.x;
                a4.y += ys[r] * wv.y;
                a4.z += ys[r] * wv.z;
                a4.w += ys[r] * wv.w;
            }
        }
#pragma unroll
        for (int o = 4; o < 64; o <<= 1) {
            a4.x += __shfl_xor(a4.x, o);
            a4.y += __shfl_xor(a4.y, o);
            a4.z += __shfl_xor(a4.z, o);
            a4.w += __shfl_xor(a4.w, o);
        }
        if (lane < 4) cred4[w4][k][lane] = a4;   // lane == cq for lanes 0..3
    }
    __syncthreads();

    // ---- phase 3: softmax ----
    if (t < 128) {                            // h = t>>4, c = t&15
        const int h = t >> 4, c = t & 15;
        float lg = bcat[h * CAT_D + c];
#pragma unroll
        for (int w = 0; w < 4; ++w)
            lg += ((const float*)cred4[w][h])[c];
        float mx = lg;
#pragma unroll
        for (int o = 8; o; o >>= 1) mx = fmaxf(mx, __shfl_xor(mx, o, 16));
        float e = __expf(lg - mx);
        float sm2 = e;
#pragma unroll
        for (int o = 8; o; o >>= 1) sm2 += __shfl_xor(sm2, o, 16);
        pcat[(size_t)b * (N_CAT * CAT_D) + t] = e / sm2;
    }
}

extern "C" void kernel_launch(void* const* d_in, const int* in_sizes, int n_in,
                              void* d_out, int out_size, void* d_ws, size_t ws_size,
                              hipStream_t stream) {
    const float* z     = (const float*)d_in[0];
    // d_in[1] = edge (unused by reference computation)
    const float* Wp    = (const float*)d_in[2];
    const float* bp    = (const float*)d_in[3];
    const float* lnw   = (const float*)d_in[4];
    const float* lnb   = (const float*)d_in[5];
    const float* Wcat  = (const float*)d_in[6];
    const float* bcat  = (const float*)d_in[7];
    const float* Wcont = (const float*)d_in[8];
    const float* bcont = (const float*)d_in[9];

    float* out    = (float*)d_out;
    float* pcat   = out;                                   // [4096, 8, 16]
    float* pcont  = out + (size_t)B_SZ * N_CAT * CAT_D;    // [4096, 24, 1]
    float* latent = pcont + (size_t)B_SZ * N_CONT;         // [4096, 32, 1024]

    u16* zb     = (u16*)d_ws;                              // 8 MB
    u16* Wt     = zb + (size_t)B_SZ * F_DIM;               // 64 MB
    float* murs = (float*)(Wt + (size_t)NTOT * F_DIM);     // 32 KB
    float* psum   = murs + 2 * B_SZ;                       // [128][4096] 2 MB
    float* psumsq = psum + (size_t)B_SZ * NSTRIP;          // 2 MB
    uint4* lnwb = (uint4*)(psumsq + (size_t)B_SZ * NSTRIP);        // 128 KB
    ushort4* wc16 = (ushort4*)(lnwb + NTOT / 4);                   // 48 KB
    u16* lat16  = (u16*)(wc16 + N_CONT * F_DIM / 4);       // 256 MB (optional)

    const size_t need = (size_t)((char*)(lat16 + (size_t)B_SZ * NTOT) - (char*)d_ws);
    const bool usebf = ws_size >= need;

    const int LDSB = 131072;
    zconv<<<dim3(B_SZ * F_DIM / 1024), 256, 0, stream>>>(z, zb);
    packln<<<dim3((NTOT / 4 + N_CONT * F_DIM / 4 + 255) / 256), 256, 0, stream>>>(
        lnw, lnb, Wcont, lnwb, wc16);
    transpose_w<<<dim3(16, 16, 32), 256, 0, stream>>>(Wp, Wt);
    if (usebf) {
        (void)hipFuncSetAttribute((const void*)gemm256<1>,
                                  hipFuncAttributeMaxDynamicSharedMemorySize, LDSB);
        gemm256<1><<<dim3(2048), 512, LDSB, stream>>>(zb, Wt, bp, lat16, nullptr,
                                                      psum, psumsq);
        ln_finalize<<<dim3(B_SZ / 64), 256, 0, stream>>>(psum, psumsq, murs);
        contK<1><<<dim3(3, B_SZ), 256, 0, stream>>>(lat16, latent, murs, lnwb, wc16,
                                                    bcont, pcont);
        catK<1><<<dim3(B_SZ), 256, 0, stream>>>(lat16, latent, murs, lnwb,
                                                Wcat, bcat, pcat);
    } else {
        (void)hipFuncSetAttribute((const void*)gemm256<0>,
                                  hipFuncAttributeMaxDynamicSharedMemorySize, LDSB);
        gemm256<0><<<dim3(2048), 512, LDSB, stream>>>(zb, Wt, bp, nullptr, latent,
                                                      psum, psumsq);
        ln_finalize<<<dim3(B_SZ / 64), 256, 0, stream>>>(psum, psumsq, murs);
        contK<0><<<dim3(3, B_SZ), 256, 0, stream>>>(latent, latent, murs, lnwb, wc16,
                                                    bcont, pcont);
        catK<0><<<dim3(B_SZ), 256, 0, stream>>>(latent, latent, murs, lnwb,
                                                Wcat, bcat, pcat);
    }
}

// Round 24
// 639.421 us; speedup vs baseline: 1.0285x; 1.0152x over previous
//
#include <hip/hip_runtime.h>

typedef unsigned short u16;
typedef unsigned int u32;
typedef __bf16 bf16x8 __attribute__((ext_vector_type(8)));
typedef float f32x4 __attribute__((ext_vector_type(4)));

#define B_SZ   4096
#define H_NUM  32
#define F_DIM  1024
#define NTOT   (H_NUM * F_DIM)   // 32768
#define N_CAT  8
#define CAT_D  16
#define N_CONT 24
#define LN_EPS 1e-5f
#define NSTRIP 128               // 256-col strips in the 256^2 GEMM

__device__ __forceinline__ u16 f2bf(float f) {
    unsigned int u = __builtin_bit_cast(unsigned int, f);
    unsigned int r = (u + 0x7FFFu + ((u >> 16) & 1u)) >> 16;
    return (u16)r;
}

__device__ __forceinline__ float bf2f(u16 v) {
    unsigned int u = ((unsigned int)v) << 16;
    return __builtin_bit_cast(float, u);
}

__device__ __forceinline__ float bflo(u32 v) { return bf2f((u16)(v & 0xffffu)); }
__device__ __forceinline__ float bfhi(u32 v) { return bf2f((u16)(v >> 16)); }

__device__ __forceinline__ void gl2lds16(const void* g, void* l) {
    __builtin_amdgcn_global_load_lds(
        (const __attribute__((address_space(1))) void*)g,
        (__attribute__((address_space(3))) void*)l,
        16, 0, 0);
}

__device__ __forceinline__ float wave_sum(float v) {
#pragma unroll
    for (int o = 32; o; o >>= 1) v += __shfl_xor(v, o);
    return v;
}

// ---------------- z f32 -> bf16 ----------------
__global__ __launch_bounds__(256) void zconv(const float* __restrict__ z,
                                             u16* __restrict__ zb) {
    int i = blockIdx.x * 256 + threadIdx.x;      // one float4 per thread
    float4 v = ((const float4*)z)[i];
    ushort4 o;
    o.x = f2bf(v.x); o.y = f2bf(v.y); o.z = f2bf(v.z); o.w = f2bf(v.w);
    ((ushort4*)zb)[i] = o;
}

// ---------------- pack lnw/lnb interleaved bf16 + Wcont bf16 ----------------
__global__ __launch_bounds__(256) void packln(const float* __restrict__ lnw,
                                              const float* __restrict__ lnb,
                                              const float* __restrict__ wcont,
                                              uint4* __restrict__ lnwb,
                                              ushort4* __restrict__ wc16) {
    int idx = blockIdx.x * 256 + threadIdx.x;
    if (idx < NTOT / 4) {
        float4 w = ((const float4*)lnw)[idx];
        float4 b = ((const float4*)lnb)[idx];
        uint4 o;
        o.x = (u32)f2bf(w.x) | ((u32)f2bf(w.y) << 16);
        o.y = (u32)f2bf(w.z) | ((u32)f2bf(w.w) << 16);
        o.z = (u32)f2bf(b.x) | ((u32)f2bf(b.y) << 16);
        o.w = (u32)f2bf(b.z) | ((u32)f2bf(b.w) << 16);
        lnwb[idx] = o;
    } else if (idx < NTOT / 4 + N_CONT * F_DIM / 4) {
        int j = idx - NTOT / 4;
        float4 v = ((const float4*)wcont)[j];
        ushort4 o;
        o.x = f2bf(v.x); o.y = f2bf(v.y); o.z = f2bf(v.z); o.w = f2bf(v.w);
        wc16[j] = o;
    }
}

// ---------------- W_proj [h][f][d] f32 -> Wt [h][d][f] bf16 ----------------
__global__ __launch_bounds__(256) void transpose_w(const float* __restrict__ W,
                                                   u16* __restrict__ Wt) {
    __shared__ u16 tile[64][72];
    const int h = blockIdx.z;
    const int f0 = blockIdx.x * 64;
    const int d0 = blockIdx.y * 64;
    const float* Wh = W + (size_t)h * F_DIM * F_DIM;
    u16* Wth = Wt + (size_t)h * F_DIM * F_DIM;
    const int t = threadIdx.x;

#pragma unroll
    for (int i = 0; i < 4; ++i) {
        int idx = i * 256 + t;        // 0..1023
        int fr = idx >> 4;            // 0..63
        int c4 = idx & 15;            // 0..15
        float4 v = *(const float4*)(Wh + (size_t)(f0 + fr) * F_DIM + d0 + c4 * 4);
        tile[fr][c4 * 4 + 0] = f2bf(v.x);
        tile[fr][c4 * 4 + 1] = f2bf(v.y);
        tile[fr][c4 * 4 + 2] = f2bf(v.z);
        tile[fr][c4 * 4 + 3] = f2bf(v.w);
    }
    __syncthreads();
#pragma unroll
    for (int i = 0; i < 2; ++i) {
        int idx = i * 256 + t;        // 0..511
        int dr = idx >> 3;            // 0..63
        int c8 = idx & 7;             // 0..7
        __attribute__((aligned(16))) u16 tmp[8];
#pragma unroll
        for (int j = 0; j < 8; ++j) tmp[j] = tile[c8 * 8 + j][dr];
        *(uint4*)(Wth + (size_t)(d0 + dr) * F_DIM + f0 + c8 * 8) = *(const uint4*)tmp;
    }
}

// ---------------- GEMM 256^2, 8 waves, 8-phase counted-vmcnt, 1 barrier/phase ----------------
// R23 change: within-XCD 4x4 super-tile block order (was m-fastest over 16x16) so
// the 32 co-resident blocks cover ~2 super-tiles: in-flight A 2MB + B 2MB <= 4MB L2
// (m-fastest re-streamed the 8MB A panel through L2 every column pass; FETCH 295MB
// vs 72MB ideal). Bijective: m_tile=(st&3)*4+(w&3), n_tile=(st>>2)*4+(w>>2).
template <int BF>
__global__ __launch_bounds__(512, 2) void gemm256(const u16* __restrict__ A,
                                                  const u16* __restrict__ Bt,
                                                  const float* __restrict__ bproj,
                                                  u16* __restrict__ lat16,
                                                  float* __restrict__ latf,
                                                  float* __restrict__ psum,
                                                  float* __restrict__ psumsq) {
    extern __shared__ u16 dynlds[];
    const int t = threadIdx.x;
    const int wid = t >> 6;            // 0..7
    const int lane = t & 63;
    const int l16 = lane & 15;
    const int lk = lane >> 4;          // 0..3
    const int wm = wid >> 2;           // 0..1  (A half / 128-row block)
    const int wn = wid & 3;            // 0..3  (64-col block)

    const int wg = blockIdx.x;
    const int xcd = wg & 7;
    const int local = wg >> 3;         // 0..255
    const int st = local >> 4;         // super-tile 0..15 (4m x 4n of 4x4 tiles)
    const int w = local & 15;          // within super-tile
    const int m0 = (((st & 3) << 2) + (w & 3)) * 256;
    const int n0 = ((xcd << 4) + ((st >> 2) << 2) + (w >> 2)) * 256;

    f32x4 acc[8][4];
    const f32x4 zero = {0.f, 0.f, 0.f, 0.f};
#pragma unroll
    for (int m = 0; m < 8; ++m)
#pragma unroll
        for (int n = 0; n < 4; ++n) acc[m][n] = zero;

    // stage half-tile p of K-tile ktn into buffer bn (2 gload_lds per thread)
    auto stage = [&](int p, int ktn, int bn) {
        const char* srcbase = (p < 2) ? (const char*)A : (const char*)Bt;
        const int rowbase = (p < 2) ? (m0 + p * 128) : (n0 + (p - 2) * 128);
        u16* ldsbase = dynlds + bn * 32768 + (p >> 1) * 16384 + (p & 1) * 8192;
#pragma unroll
        for (int i = 0; i < 2; ++i) {
            int oo = i * 8192 + t * 16;                  // byte off in 16KB half
            int oos = oo ^ (((oo >> 7) & 7) << 4);       // pre-swizzled source
            int row = oo >> 7;
            int colb = oos & 127;
            gl2lds16(srcbase + (size_t)(rowbase + row) * 2048 + ktn * 128 + colb,
                     ldsbase + i * 4096 + (wid << 9));   // wave-uniform dest (u16 units)
        }
    };

    // prologue: kt0 complete + kt1's B halves (6 half-tiles, 12 loads/wave)
    stage(0, 0, 0); stage(1, 0, 0); stage(2, 0, 0); stage(3, 0, 0);
    stage(2, 1, 1); stage(3, 1, 1);
    asm volatile("s_waitcnt vmcnt(4)" ::: "memory");   // kt0's 4 halves landed
    asm volatile("s_barrier" ::: "memory");

    const int swz = (l16 & 7) << 4;                      // read-side XOR (bytes)
    for (int kt = 0; kt < 16; ++kt) {
        const int buf = kt & 1;
        const char* aB = (const char*)(dynlds + buf * 32768 + wm * 8192);
        const char* bB = (const char*)(dynlds + buf * 32768 + 16384 + (wn >> 1) * 8192);

        bf16x8 bfr[4][2];
#pragma unroll
        for (int p = 0; p < 4; ++p) {
            if (p == 0) {
#pragma unroll
                for (int nr = 0; nr < 4; ++nr)
#pragma unroll
                    for (int kk = 0; kk < 2; ++kk)
                        bfr[nr][kk] = *(const bf16x8*)(bB +
                            ((wn & 1) * 64 + nr * 16 + l16) * 128 +
                            ((kk * 64 + lk * 16) ^ swz));
            }
            bf16x8 afr[2][2];
#pragma unroll
            for (int mr = 0; mr < 2; ++mr)
#pragma unroll
                for (int kk = 0; kk < 2; ++kk)
                    afr[mr][kk] = *(const bf16x8*)(aB +
                        (p * 32 + mr * 16 + l16) * 128 +
                        ((kk * 64 + lk * 16) ^ swz));

            // stage exactly one half-tile this phase (dead-target proven)
            if (p == 0 && kt + 1 < 16) stage(0, kt + 1, buf ^ 1);
            if (p == 1 && kt + 1 < 16) stage(1, kt + 1, buf ^ 1);
            if (p == 2 && kt + 2 < 16) stage(2, kt + 2, buf);
            if (p == 3 && kt + 2 < 16) stage(3, kt + 2, buf);

            __builtin_amdgcn_s_setprio(1);
#pragma unroll
            for (int kk = 0; kk < 2; ++kk)
#pragma unroll
                for (int mr = 0; mr < 2; ++mr)
#pragma unroll
                    for (int nr = 0; nr < 4; ++nr)
                        acc[p * 2 + mr][nr] = __builtin_amdgcn_mfma_f32_16x16x32_bf16(
                            afr[mr][kk], bfr[nr][kk], acc[p * 2 + mr][nr], 0, 0, 0);
            __builtin_amdgcn_s_setprio(0);
            if (p == 3) {
                if (kt < 14)       asm volatile("s_waitcnt vmcnt(4)" ::: "memory");
                else if (kt == 14) asm volatile("s_waitcnt vmcnt(0)" ::: "memory");
            }
            asm volatile("s_barrier" ::: "memory");      // phase end (only barrier)
        }
    }

    // ---- epilogue: bf16 latent store + LN partials (reuse dead LDS) ----
    float bias[4];
#pragma unroll
    for (int nr = 0; nr < 4; ++nr) bias[nr] = bproj[n0 + wn * 64 + nr * 16 + l16];

    float sm[8][4], s2[8][4];
#pragma unroll
    for (int mr = 0; mr < 8; ++mr)
#pragma unroll
        for (int j = 0; j < 4; ++j) { sm[mr][j] = 0.f; s2[mr][j] = 0.f; }

#pragma unroll
    for (int mr = 0; mr < 8; ++mr) {
#pragma unroll
        for (int j = 0; j < 4; ++j) {
            const int rowg = m0 + wm * 128 + mr * 16 + lk * 4 + j;
            size_t off = (size_t)rowg * NTOT + n0 + wn * 64 + l16;
#pragma unroll
            for (int nr = 0; nr < 4; ++nr) {
                float v = acc[mr][nr][j] + bias[nr];
                if (BF) lat16[off + nr * 16] = f2bf(v);
                else    latf[off + nr * 16] = v;
                sm[mr][j] += v;
                s2[mr][j] += v * v;
            }
        }
    }
#pragma unroll
    for (int o = 1; o < 16; o <<= 1) {
#pragma unroll
        for (int mr = 0; mr < 8; ++mr)
#pragma unroll
            for (int j = 0; j < 4; ++j) {
                sm[mr][j] += __shfl_xor(sm[mr][j], o);
                s2[mr][j] += __shfl_xor(s2[mr][j], o);
            }
    }
    float* sredf = (float*)dynlds;            // [4][256]  (aliases dead buffers)
    float* s2f   = sredf + 1024;              // [4][256]
    __syncthreads();
    if (l16 == 0) {
#pragma unroll
        for (int mr = 0; mr < 8; ++mr)
#pragma unroll
            for (int j = 0; j < 4; ++j) {
                int r = wm * 128 + mr * 16 + lk * 4 + j;
                sredf[wn * 256 + r] = sm[mr][j];
                s2f[wn * 256 + r] = s2[mr][j];
            }
    }
    __syncthreads();
    if (t < 256) {
        const int strip = n0 >> 8;
        float S = sredf[t] + sredf[256 + t] + sredf[512 + t] + sredf[768 + t];
        float S2 = s2f[t] + s2f[256 + t] + s2f[512 + t] + s2f[768 + t];
        psum[(size_t)strip * B_SZ + m0 + t] = S;
        psumsq[(size_t)strip * B_SZ + m0 + t] = S2;
    }
}

// ---------------- finalize LN stats from partials (psum layout [strip][b]) ----------------
__global__ __launch_bounds__(256) void ln_finalize(const float* __restrict__ psum,
                                                   const float* __restrict__ psumsq,
                                                   float* __restrict__ murs) {
    const int t = threadIdx.x;
    const int b0 = blockIdx.x * 64;
    const int tb = t & 63;            // which b
    const int tg = t >> 6;            // strip group 0..3
    float s = 0.f, s2 = 0.f;
    for (int sidx = tg; sidx < NSTRIP; sidx += 4) {
        s += psum[(size_t)sidx * B_SZ + b0 + tb];
        s2 += psumsq[(size_t)sidx * B_SZ + b0 + tb];
    }
    __shared__ float r1[4][64], r2[4][64];
    r1[tg][tb] = s;
    r2[tg][tb] = s2;
    __syncthreads();
    if (t < 64) {
        float S = r1[0][t] + r1[1][t] + r1[2][t] + r1[3][t];
        float S2 = r2[0][t] + r2[1][t] + r2[2][t] + r2[3][t];
        float m = S / (float)NTOT;
        float var = S2 / (float)NTOT - m * m;
        murs[b0 + t] = m;
        murs[B_SZ + b0 + t] = rsqrtf(var + LN_EPS);
    }
}

// ---------------- cont heads: pure streaming, zero barriers in stream ----------------
template <int BF>
__global__ __launch_bounds__(256) void contK(const void* __restrict__ latin_,
                                             float* __restrict__ latout,
                                             const float* __restrict__ murs,
                                             const uint4* __restrict__ lnwb,
                                             const ushort4* __restrict__ wc16,
                                             const float* __restrict__ bcont,
                                             float* __restrict__ pcont) {
    const int g = blockIdx.x;                 // 0..2 (fastest: 3 blocks share b)
    const int b = blockIdx.y;
    const int t = threadIdx.x;
    const int lane = t & 63;
    const int w4 = t >> 6;
    const float mu = murs[b];
    const float rs = murs[B_SZ + b];
    const ushort4* lin16 = (const ushort4*)((const u16*)latin_ + (size_t)b * NTOT);
    const float4*  linf  = (const float4*)((const float*)latin_ + (size_t)b * NTOT);
    float4* lout4 = (float4*)(latout + (size_t)b * NTOT);

    __shared__ float red[8][4];

    float cp8[8];
#pragma unroll
    for (int j = 0; j < 8; ++j) {
        const int k = N_CAT + g * 8 + j;
        const int i = (k << 8) + t;
        float4 x;
        if (BF) {
            ushort4 xv = lin16[i];
            x.x = bf2f(xv.x); x.y = bf2f(xv.y); x.z = bf2f(xv.z); x.w = bf2f(xv.w);
        } else {
            x = linf[i];
        }
        uint4 wb = lnwb[i];
        ushort4 wv = wc16[((g * 8 + j) << 8) + t];
        float4 yo;
        yo.x = fmaxf(0.f, (x.x - mu) * rs * bflo(wb.x) + bflo(wb.z));
        yo.y = fmaxf(0.f, (x.y - mu) * rs * bfhi(wb.x) + bfhi(wb.z));
        yo.z = fmaxf(0.f, (x.z - mu) * rs * bflo(wb.y) + bflo(wb.w));
        yo.w = fmaxf(0.f, (x.w - mu) * rs * bfhi(wb.y) + bfhi(wb.w));
        lout4[i] = yo;
        cp8[j] = yo.x * bf2f(wv.x) + yo.y * bf2f(wv.y) +
                 yo.z * bf2f(wv.z) + yo.w * bf2f(wv.w);
    }
#pragma unroll
    for (int j = 0; j < 8; ++j) {
        float v = wave_sum(cp8[j]);
        if (lane == 0) red[j][w4] = v;
    }
    __syncthreads();
    if (t < 8) {
        const int ci = g * 8 + t;
        pcont[(size_t)b * N_CONT + ci] =
            red[t][0] + red[t][1] + red[t][2] + red[t][3] + bcont[ci];
    }
}

// ---------------- cat heads: normalize + stage + GEMV + softmax, one block per b ----------------
template <int BF>
__global__ __launch_bounds__(256) void catK(const void* __restrict__ latin_,
                                            float* __restrict__ latout,
                                            const float* __restrict__ murs,
                                            const uint4* __restrict__ lnwb,
                                            const float* __restrict__ Wcat,
                                            const float* __restrict__ bcat,
                                            float* __restrict__ pcat) {
    const int b = blockIdx.x;
    const int t = threadIdx.x;
    const int lane = t & 63;
    const int w4 = t >> 6;                    // wave 0..3
    const float mu = murs[b];
    const float rs = murs[B_SZ + b];
    const ushort4* lin16 = (const ushort4*)((const u16*)latin_ + (size_t)b * NTOT);
    const float4*  linf  = (const float4*)((const float*)latin_ + (size_t)b * NTOT);
    float4* lout4 = (float4*)(latout + (size_t)b * NTOT);

    __shared__ ushort4 sy16[N_CAT * 256];     // 8 cat heads' y, bf16 (16 KB)
    __shared__ float4 cred4[4][N_CAT][4];     // [wave][h][cq] partials (2 KB)

    // ---- phase 1: normalize, store, stage y (fully unrolled, no barriers) ----
#pragma unroll
    for (int k = 0; k < N_CAT; ++k) {
        const int i = (k << 8) + t;
        float4 x;
        if (BF) {
            ushort4 xv = lin16[i];
            x.x = bf2f(xv.x); x.y = bf2f(xv.y); x.z = bf2f(xv.z); x.w = bf2f(xv.w);
        } else {
            x = linf[i];
        }
        uint4 wb = lnwb[i];
        float4 yo;
        yo.x = fmaxf(0.f, (x.x - mu) * rs * bflo(wb.x) + bflo(wb.z));
        yo.y = fmaxf(0.f, (x.y - mu) * rs * bfhi(wb.x) + bfhi(wb.z));
        yo.z = fmaxf(0.f, (x.z - mu) * rs * bflo(wb.y) + bflo(wb.w));
        yo.w = fmaxf(0.f, (x.w - mu) * rs * bfhi(wb.y) + bfhi(wb.w));
        lout4[i] = yo;
        ushort4 ys;
        ys.x = f2bf(yo.x); ys.y = f2bf(yo.y); ys.z = f2bf(yo.z); ys.w = f2bf(yo.w);
        sy16[i] = ys;                          // own slot, no race
    }
    __syncthreads();

    // ---- phase 2: cat GEMVs from LDS, float4 Wcat (cq = t&3, fg = t>>2) ----
    const int cq = t & 3;
    const int fg = t >> 2;                    // 0..63
    for (int k = 0; k < N_CAT; ++k) {
        const float4* Wc4 = (const float4*)(Wcat + (size_t)k * F_DIM * CAT_D);
        float4 a4 = {0.f, 0.f, 0.f, 0.f};
#pragma unroll
        for (int jq = 0; jq < 4; ++jq) {
            ushort4 yv = sy16[(k << 8) + fg * 4 + jq];
            float ys[4] = {bf2f(yv.x), bf2f(yv.y), bf2f(yv.z), bf2f(yv.w)};
#pragma unroll
            for (int r = 0; r < 4; ++r) {
                int f = fg * 16 + jq * 4 + r;
                float4 wv = Wc4[f * 4 + cq];
                a4.x += ys[r] * wv.x;
                a4.y += ys[r] * wv.y;
                a4.z += ys[r] * wv.z;
                a4.w += ys[r] * wv.w;
            }
        }
#pragma unroll
        for (int o = 4; o < 64; o <<= 1) {
            a4.x += __shfl_xor(a4.x, o);
            a4.y += __shfl_xor(a4.y, o);
            a4.z += __shfl_xor(a4.z, o);
            a4.w += __shfl_xor(a4.w, o);
        }
        if (lane < 4) cred4[w4][k][lane] = a4;   // lane == cq for lanes 0..3
    }
    __syncthreads();

    // ---- phase 3: softmax ----
    if (t < 128) {                            // h = t>>4, c = t&15
        const int h = t >> 4, c = t & 15;
        float lg = bcat[h * CAT_D + c];
#pragma unroll
        for (int w = 0; w < 4; ++w)
            lg += ((const float*)cred4[w][h])[c];
        float mx = lg;
#pragma unroll
        for (int o = 8; o; o >>= 1) mx = fmaxf(mx, __shfl_xor(mx, o, 16));
        float e = __expf(lg - mx);
        float sm2 = e;
#pragma unroll
        for (int o = 8; o; o >>= 1) sm2 += __shfl_xor(sm2, o, 16);
        pcat[(size_t)b * (N_CAT * CAT_D) + t] = e / sm2;
    }
}

extern "C" void kernel_launch(void* const* d_in, const int* in_sizes, int n_in,
                              void* d_out, int out_size, void* d_ws, size_t ws_size,
                              hipStream_t stream) {
    const float* z     = (const float*)d_in[0];
    // d_in[1] = edge (unused by reference computation)
    const float* Wp    = (const float*)d_in[2];
    const float* bp    = (const float*)d_in[3];
    const float* lnw   = (const float*)d_in[4];
    const float* lnb   = (const float*)d_in[5];
    const float* Wcat  = (const float*)d_in[6];
    const float* bcat  = (const float*)d_in[7];
    const float* Wcont = (const float*)d_in[8];
    const float* bcont = (const float*)d_in[9];

    float* out    = (float*)d_out;
    float* pcat   = out;                                   // [4096, 8, 16]
    float* pcont  = out + (size_t)B_SZ * N_CAT * CAT_D;    // [4096, 24, 1]
    float* latent = pcont + (size_t)B_SZ * N_CONT;         // [4096, 32, 1024]

    u16* zb     = (u16*)d_ws;                              // 8 MB
    u16* Wt     = zb + (size_t)B_SZ * F_DIM;               // 64 MB
    float* murs = (float*)(Wt + (size_t)NTOT * F_DIM);     // 32 KB
    float* psum   = murs + 2 * B_SZ;                       // [128][4096] 2 MB
    float* psumsq = psum + (size_t)B_SZ * NSTRIP;          // 2 MB
    uint4* lnwb = (uint4*)(psumsq + (size_t)B_SZ * NSTRIP);        // 128 KB
    ushort4* wc16 = (ushort4*)(lnwb + NTOT / 4);                   // 48 KB
    u16* lat16  = (u16*)(wc16 + N_CONT * F_DIM / 4);       // 256 MB (optional)

    const size_t need = (size_t)((char*)(lat16 + (size_t)B_SZ * NTOT) - (char*)d_ws);
    const bool usebf = ws_size >= need;

    const int LDSB = 131072;
    zconv<<<dim3(B_SZ * F_DIM / 1024), 256, 0, stream>>>(z, zb);
    packln<<<dim3((NTOT / 4 + N_CONT * F_DIM / 4 + 255) / 256), 256, 0, stream>>>(
        lnw, lnb, Wcont, lnwb, wc16);
    transpose_w<<<dim3(16, 16, 32), 256, 0, stream>>>(Wp, Wt);
    if (usebf) {
        (void)hipFuncSetAttribute((const void*)gemm256<1>,
                                  hipFuncAttributeMaxDynamicSharedMemorySize, LDSB);
        gemm256<1><<<dim3(2048), 512, LDSB, stream>>>(zb, Wt, bp, lat16, nullptr,
                                                      psum, psumsq);
        ln_finalize<<<dim3(B_SZ / 64), 256, 0, stream>>>(psum, psumsq, murs);
        contK<1><<<dim3(3, B_SZ), 256, 0, stream>>>(lat16, latent, murs, lnwb, wc16,
                                                    bcont, pcont);
        catK<1><<<dim3(B_SZ), 256, 0, stream>>>(lat16, latent, murs, lnwb,
                                                Wcat, bcat, pcat);
    } else {
        (void)hipFuncSetAttribute((const void*)gemm256<0>,
                                  hipFuncAttributeMaxDynamicSharedMemorySize, LDSB);
        gemm256<0><<<dim3(2048), 512, LDSB, stream>>>(zb, Wt, bp, nullptr, latent,
                                                      psum, psumsq);
        ln_finalize<<<dim3(B_SZ / 64), 256, 0, stream>>>(psum, psumsq, murs);
        contK<0><<<dim3(3, B_SZ), 256, 0, stream>>>(latent, latent, murs, lnwb, wc16,
                                                    bcont, pcont);
        catK<0><<<dim3(B_SZ), 256, 0, stream>>>(latent, latent, murs, lnwb,
                                                Wcat, bcat, pcat);
    }
}

// Round 25
// 637.103 us; speedup vs baseline: 1.0322x; 1.0036x over previous
//
#include <hip/hip_runtime.h>

typedef unsigned short u16;
typedef unsigned int u32;
typedef __bf16 bf16x8 __attribute__((ext_vector_type(8)));
typedef float f32x4 __attribute__((ext_vector_type(4)));

#define B_SZ   4096
#define H_NUM  32
#define F_DIM  1024
#define NTOT   (H_NUM * F_DIM)   // 32768
#define N_CAT  8
#define CAT_D  16
#define N_CONT 24
#define LN_EPS 1e-5f
#define NSTRIP 128               // 256-col strips in the 256^2 GEMM

__device__ __forceinline__ u16 f2bf(float f) {
    unsigned int u = __builtin_bit_cast(unsigned int, f);
    unsigned int r = (u + 0x7FFFu + ((u >> 16) & 1u)) >> 16;
    return (u16)r;
}

__device__ __forceinline__ float bf2f(u16 v) {
    unsigned int u = ((unsigned int)v) << 16;
    return __builtin_bit_cast(float, u);
}

__device__ __forceinline__ float bflo(u32 v) { return bf2f((u16)(v & 0xffffu)); }
__device__ __forceinline__ float bfhi(u32 v) { return bf2f((u16)(v >> 16)); }

__device__ __forceinline__ void gl2lds16(const void* g, void* l) {
    __builtin_amdgcn_global_load_lds(
        (const __attribute__((address_space(1))) void*)g,
        (__attribute__((address_space(3))) void*)l,
        16, 0, 0);
}

__device__ __forceinline__ float wave_sum(float v) {
#pragma unroll
    for (int o = 32; o; o >>= 1) v += __shfl_xor(v, o);
    return v;
}

// ---------------- z f32 -> bf16 ----------------
__global__ __launch_bounds__(256) void zconv(const float* __restrict__ z,
                                             u16* __restrict__ zb) {
    int i = blockIdx.x * 256 + threadIdx.x;      // one float4 per thread
    float4 v = ((const float4*)z)[i];
    ushort4 o;
    o.x = f2bf(v.x); o.y = f2bf(v.y); o.z = f2bf(v.z); o.w = f2bf(v.w);
    ((ushort4*)zb)[i] = o;
}

// ---------------- pack lnw/lnb interleaved bf16 + Wcont bf16 ----------------
__global__ __launch_bounds__(256) void packln(const float* __restrict__ lnw,
                                              const float* __restrict__ lnb,
                                              const float* __restrict__ wcont,
                                              uint4* __restrict__ lnwb,
                                              ushort4* __restrict__ wc16) {
    int idx = blockIdx.x * 256 + threadIdx.x;
    if (idx < NTOT / 4) {
        float4 w = ((const float4*)lnw)[idx];
        float4 b = ((const float4*)lnb)[idx];
        uint4 o;
        o.x = (u32)f2bf(w.x) | ((u32)f2bf(w.y) << 16);
        o.y = (u32)f2bf(w.z) | ((u32)f2bf(w.w) << 16);
        o.z = (u32)f2bf(b.x) | ((u32)f2bf(b.y) << 16);
        o.w = (u32)f2bf(b.z) | ((u32)f2bf(b.w) << 16);
        lnwb[idx] = o;
    } else if (idx < NTOT / 4 + N_CONT * F_DIM / 4) {
        int j = idx - NTOT / 4;
        float4 v = ((const float4*)wcont)[j];
        ushort4 o;
        o.x = f2bf(v.x); o.y = f2bf(v.y); o.z = f2bf(v.z); o.w = f2bf(v.w);
        wc16[j] = o;
    }
}

// ---------------- W_proj [h][f][d] f32 -> Wt [h][d][f] bf16 ----------------
__global__ __launch_bounds__(256) void transpose_w(const float* __restrict__ W,
                                                   u16* __restrict__ Wt) {
    __shared__ u16 tile[64][72];
    const int h = blockIdx.z;
    const int f0 = blockIdx.x * 64;
    const int d0 = blockIdx.y * 64;
    const float* Wh = W + (size_t)h * F_DIM * F_DIM;
    u16* Wth = Wt + (size_t)h * F_DIM * F_DIM;
    const int t = threadIdx.x;

#pragma unroll
    for (int i = 0; i < 4; ++i) {
        int idx = i * 256 + t;        // 0..1023
        int fr = idx >> 4;            // 0..63
        int c4 = idx & 15;            // 0..15
        float4 v = *(const float4*)(Wh + (size_t)(f0 + fr) * F_DIM + d0 + c4 * 4);
        tile[fr][c4 * 4 + 0] = f2bf(v.x);
        tile[fr][c4 * 4 + 1] = f2bf(v.y);
        tile[fr][c4 * 4 + 2] = f2bf(v.z);
        tile[fr][c4 * 4 + 3] = f2bf(v.w);
    }
    __syncthreads();
#pragma unroll
    for (int i = 0; i < 2; ++i) {
        int idx = i * 256 + t;        // 0..511
        int dr = idx >> 3;            // 0..63
        int c8 = idx & 7;             // 0..7
        __attribute__((aligned(16))) u16 tmp[8];
#pragma unroll
        for (int j = 0; j < 8; ++j) tmp[j] = tile[c8 * 8 + j][dr];
        *(uint4*)(Wth + (size_t)(d0 + dr) * F_DIM + f0 + c8 * 8) = *(const uint4*)tmp;
    }
}

// ---------------- GEMM 256^2, 8-phase counted-vmcnt, pipelined frag reads ----------------
// R24 change: A-fragment ds_reads for phase p+1 are issued BEFORE phase p's MFMA
// cluster (ping-pong afr[2]) so the ~120cy LDS latency hides under the 16-MFMA
// cluster instead of sitting after each barrier. All reads target buf (landed
// since kt start); stages touch buf^1-A / buf-B only (disjoint). +16 VGPR.
template <int BF>
__global__ __launch_bounds__(512, 2) void gemm256(const u16* __restrict__ A,
                                                  const u16* __restrict__ Bt,
                                                  const float* __restrict__ bproj,
                                                  u16* __restrict__ lat16,
                                                  float* __restrict__ latf,
                                                  float* __restrict__ psum,
                                                  float* __restrict__ psumsq) {
    extern __shared__ u16 dynlds[];
    const int t = threadIdx.x;
    const int wid = t >> 6;            // 0..7
    const int lane = t & 63;
    const int l16 = lane & 15;
    const int lk = lane >> 4;          // 0..3
    const int wm = wid >> 2;           // 0..1  (A half / 128-row block)
    const int wn = wid & 3;            // 0..3  (64-col block)

    const int wg = blockIdx.x;
    const int xcd = wg & 7;
    const int local = wg >> 3;         // 0..255
    const int st = local >> 4;         // super-tile 0..15 (4m x 4n of 4x4 tiles)
    const int w = local & 15;          // within super-tile
    const int m0 = (((st & 3) << 2) + (w & 3)) * 256;
    const int n0 = ((xcd << 4) + ((st >> 2) << 2) + (w >> 2)) * 256;

    f32x4 acc[8][4];
    const f32x4 zero = {0.f, 0.f, 0.f, 0.f};
#pragma unroll
    for (int m = 0; m < 8; ++m)
#pragma unroll
        for (int n = 0; n < 4; ++n) acc[m][n] = zero;

    // stage half-tile p of K-tile ktn into buffer bn (2 gload_lds per thread)
    auto stage = [&](int p, int ktn, int bn) {
        const char* srcbase = (p < 2) ? (const char*)A : (const char*)Bt;
        const int rowbase = (p < 2) ? (m0 + p * 128) : (n0 + (p - 2) * 128);
        u16* ldsbase = dynlds + bn * 32768 + (p >> 1) * 16384 + (p & 1) * 8192;
#pragma unroll
        for (int i = 0; i < 2; ++i) {
            int oo = i * 8192 + t * 16;                  // byte off in 16KB half
            int oos = oo ^ (((oo >> 7) & 7) << 4);       // pre-swizzled source
            int row = oo >> 7;
            int colb = oos & 127;
            gl2lds16(srcbase + (size_t)(rowbase + row) * 2048 + ktn * 128 + colb,
                     ldsbase + i * 4096 + (wid << 9));   // wave-uniform dest (u16 units)
        }
    };

    // prologue: kt0 complete + kt1's B halves (6 half-tiles, 12 loads/wave)
    stage(0, 0, 0); stage(1, 0, 0); stage(2, 0, 0); stage(3, 0, 0);
    stage(2, 1, 1); stage(3, 1, 1);
    asm volatile("s_waitcnt vmcnt(4)" ::: "memory");   // kt0's 4 halves landed
    asm volatile("s_barrier" ::: "memory");

    const int swz = (l16 & 7) << 4;                      // read-side XOR (bytes)
    for (int kt = 0; kt < 16; ++kt) {
        const int buf = kt & 1;
        const char* aB = (const char*)(dynlds + buf * 32768 + wm * 8192);
        const char* bB = (const char*)(dynlds + buf * 32768 + 16384 + (wn >> 1) * 8192);

        bf16x8 bfr[4][2];
#pragma unroll
        for (int nr = 0; nr < 4; ++nr)
#pragma unroll
            for (int kk = 0; kk < 2; ++kk)
                bfr[nr][kk] = *(const bf16x8*)(bB +
                    ((wn & 1) * 64 + nr * 16 + l16) * 128 +
                    ((kk * 64 + lk * 16) ^ swz));

        bf16x8 afr[2][2][2];      // ping-pong by phase parity
#pragma unroll
        for (int mr = 0; mr < 2; ++mr)
#pragma unroll
            for (int kk = 0; kk < 2; ++kk)
                afr[0][mr][kk] = *(const bf16x8*)(aB +
                    (0 * 32 + mr * 16 + l16) * 128 +
                    ((kk * 64 + lk * 16) ^ swz));

#pragma unroll
        for (int p = 0; p < 4; ++p) {
            // stage exactly one half-tile this phase (dead-target proven)
            if (p == 0 && kt + 1 < 16) stage(0, kt + 1, buf ^ 1);
            if (p == 1 && kt + 1 < 16) stage(1, kt + 1, buf ^ 1);
            if (p == 2 && kt + 2 < 16) stage(2, kt + 2, buf);
            if (p == 3 && kt + 2 < 16) stage(3, kt + 2, buf);

            // prefetch next phase's A-frags: latency hides under this MFMA cluster
            if (p < 3) {
#pragma unroll
                for (int mr = 0; mr < 2; ++mr)
#pragma unroll
                    for (int kk = 0; kk < 2; ++kk)
                        afr[(p + 1) & 1][mr][kk] = *(const bf16x8*)(aB +
                            ((p + 1) * 32 + mr * 16 + l16) * 128 +
                            ((kk * 64 + lk * 16) ^ swz));
            }

            __builtin_amdgcn_s_setprio(1);
#pragma unroll
            for (int kk = 0; kk < 2; ++kk)
#pragma unroll
                for (int mr = 0; mr < 2; ++mr)
#pragma unroll
                    for (int nr = 0; nr < 4; ++nr)
                        acc[p * 2 + mr][nr] = __builtin_amdgcn_mfma_f32_16x16x32_bf16(
                            afr[p & 1][mr][kk], bfr[nr][kk], acc[p * 2 + mr][nr], 0, 0, 0);
            __builtin_amdgcn_s_setprio(0);
            if (p == 3) {
                if (kt < 14)       asm volatile("s_waitcnt vmcnt(4)" ::: "memory");
                else if (kt == 14) asm volatile("s_waitcnt vmcnt(0)" ::: "memory");
            }
            asm volatile("s_barrier" ::: "memory");      // phase end (only barrier)
        }
    }

    // ---- epilogue: bf16 latent store + LN partials (reuse dead LDS) ----
    float bias[4];
#pragma unroll
    for (int nr = 0; nr < 4; ++nr) bias[nr] = bproj[n0 + wn * 64 + nr * 16 + l16];

    float sm[8][4], s2[8][4];
#pragma unroll
    for (int mr = 0; mr < 8; ++mr)
#pragma unroll
        for (int j = 0; j < 4; ++j) { sm[mr][j] = 0.f; s2[mr][j] = 0.f; }

#pragma unroll
    for (int mr = 0; mr < 8; ++mr) {
#pragma unroll
        for (int j = 0; j < 4; ++j) {
            const int rowg = m0 + wm * 128 + mr * 16 + lk * 4 + j;
            size_t off = (size_t)rowg * NTOT + n0 + wn * 64 + l16;
#pragma unroll
            for (int nr = 0; nr < 4; ++nr) {
                float v = acc[mr][nr][j] + bias[nr];
                if (BF) lat16[off + nr * 16] = f2bf(v);
                else    latf[off + nr * 16] = v;
                sm[mr][j] += v;
                s2[mr][j] += v * v;
            }
        }
    }
#pragma unroll
    for (int o = 1; o < 16; o <<= 1) {
#pragma unroll
        for (int mr = 0; mr < 8; ++mr)
#pragma unroll
            for (int j = 0; j < 4; ++j) {
                sm[mr][j] += __shfl_xor(sm[mr][j], o);
                s2[mr][j] += __shfl_xor(s2[mr][j], o);
            }
    }
    float* sredf = (float*)dynlds;            // [4][256]  (aliases dead buffers)
    float* s2f   = sredf + 1024;              // [4][256]
    __syncthreads();
    if (l16 == 0) {
#pragma unroll
        for (int mr = 0; mr < 8; ++mr)
#pragma unroll
            for (int j = 0; j < 4; ++j) {
                int r = wm * 128 + mr * 16 + lk * 4 + j;
                sredf[wn * 256 + r] = sm[mr][j];
                s2f[wn * 256 + r] = s2[mr][j];
            }
    }
    __syncthreads();
    if (t < 256) {
        const int strip = n0 >> 8;
        float S = sredf[t] + sredf[256 + t] + sredf[512 + t] + sredf[768 + t];
        float S2 = s2f[t] + s2f[256 + t] + s2f[512 + t] + s2f[768 + t];
        psum[(size_t)strip * B_SZ + m0 + t] = S;
        psumsq[(size_t)strip * B_SZ + m0 + t] = S2;
    }
}

// ---------------- finalize LN stats from partials (psum layout [strip][b]) ----------------
__global__ __launch_bounds__(256) void ln_finalize(const float* __restrict__ psum,
                                                   const float* __restrict__ psumsq,
                                                   float* __restrict__ murs) {
    const int t = threadIdx.x;
    const int b0 = blockIdx.x * 64;
    const int tb = t & 63;            // which b
    const int tg = t >> 6;            // strip group 0..3
    float s = 0.f, s2 = 0.f;
    for (int sidx = tg; sidx < NSTRIP; sidx += 4) {
        s += psum[(size_t)sidx * B_SZ + b0 + tb];
        s2 += psumsq[(size_t)sidx * B_SZ + b0 + tb];
    }
    __shared__ float r1[4][64], r2[4][64];
    r1[tg][tb] = s;
    r2[tg][tb] = s2;
    __syncthreads();
    if (t < 64) {
        float S = r1[0][t] + r1[1][t] + r1[2][t] + r1[3][t];
        float S2 = r2[0][t] + r2[1][t] + r2[2][t] + r2[3][t];
        float m = S / (float)NTOT;
        float var = S2 / (float)NTOT - m * m;
        murs[b0 + t] = m;
        murs[B_SZ + b0 + t] = rsqrtf(var + LN_EPS);
    }
}

// ---------------- cont heads: pure streaming, zero barriers in stream ----------------
template <int BF>
__global__ __launch_bounds__(256) void contK(const void* __restrict__ latin_,
                                             float* __restrict__ latout,
                                             const float* __restrict__ murs,
                                             const uint4* __restrict__ lnwb,
                                             const ushort4* __restrict__ wc16,
                                             const float* __restrict__ bcont,
                                             float* __restrict__ pcont) {
    const int g = blockIdx.x;                 // 0..2 (fastest: 3 blocks share b)
    const int b = blockIdx.y;
    const int t = threadIdx.x;
    const int lane = t & 63;
    const int w4 = t >> 6;
    const float mu = murs[b];
    const float rs = murs[B_SZ + b];
    const ushort4* lin16 = (const ushort4*)((const u16*)latin_ + (size_t)b * NTOT);
    const float4*  linf  = (const float4*)((const float*)latin_ + (size_t)b * NTOT);
    float4* lout4 = (float4*)(latout + (size_t)b * NTOT);

    __shared__ float red[8][4];

    float cp8[8];
#pragma unroll
    for (int j = 0; j < 8; ++j) {
        const int k = N_CAT + g * 8 + j;
        const int i = (k << 8) + t;
        float4 x;
        if (BF) {
            ushort4 xv = lin16[i];
            x.x = bf2f(xv.x); x.y = bf2f(xv.y); x.z = bf2f(xv.z); x.w = bf2f(xv.w);
        } else {
            x = linf[i];
        }
        uint4 wb = lnwb[i];
        ushort4 wv = wc16[((g * 8 + j) << 8) + t];
        float4 yo;
        yo.x = fmaxf(0.f, (x.x - mu) * rs * bflo(wb.x) + bflo(wb.z));
        yo.y = fmaxf(0.f, (x.y - mu) * rs * bfhi(wb.x) + bfhi(wb.z));
        yo.z = fmaxf(0.f, (x.z - mu) * rs * bflo(wb.y) + bflo(wb.w));
        yo.w = fmaxf(0.f, (x.w - mu) * rs * bfhi(wb.y) + bfhi(wb.w));
        lout4[i] = yo;
        cp8[j] = yo.x * bf2f(wv.x) + yo.y * bf2f(wv.y) +
                 yo.z * bf2f(wv.z) + yo.w * bf2f(wv.w);
    }
#pragma unroll
    for (int j = 0; j < 8; ++j) {
        float v = wave_sum(cp8[j]);
        if (lane == 0) red[j][w4] = v;
    }
    __syncthreads();
    if (t < 8) {
        const int ci = g * 8 + t;
        pcont[(size_t)b * N_CONT + ci] =
            red[t][0] + red[t][1] + red[t][2] + red[t][3] + bcont[ci];
    }
}

// ---------------- cat heads: normalize + stage + GEMV + softmax, one block per b ----------------
template <int BF>
__global__ __launch_bounds__(256) void catK(const void* __restrict__ latin_,
                                            float* __restrict__ latout,
                                            const float* __restrict__ murs,
                                            const uint4* __restrict__ lnwb,
                                            const float* __restrict__ Wcat,
                                            const float* __restrict__ bcat,
                                            float* __restrict__ pcat) {
    const int b = blockIdx.x;
    const int t = threadIdx.x;
    const int lane = t & 63;
    const int w4 = t >> 6;                    // wave 0..3
    const float mu = murs[b];
    const float rs = murs[B_SZ + b];
    const ushort4* lin16 = (const ushort4*)((const u16*)latin_ + (size_t)b * NTOT);
    const float4*  linf  = (const float4*)((const float*)latin_ + (size_t)b * NTOT);
    float4* lout4 = (float4*)(latout + (size_t)b * NTOT);

    __shared__ ushort4 sy16[N_CAT * 256];     // 8 cat heads' y, bf16 (16 KB)
    __shared__ float4 cred4[4][N_CAT][4];     // [wave][h][cq] partials (2 KB)

    // ---- phase 1: normalize, store, stage y (fully unrolled, no barriers) ----
#pragma unroll
    for (int k = 0; k < N_CAT; ++k) {
        const int i = (k << 8) + t;
        float4 x;
        if (BF) {
            ushort4 xv = lin16[i];
            x.x = bf2f(xv.x); x.y = bf2f(xv.y); x.z = bf2f(xv.z); x.w = bf2f(xv.w);
        } else {
            x = linf[i];
        }
        uint4 wb = lnwb[i];
        float4 yo;
        yo.x = fmaxf(0.f, (x.x - mu) * rs * bflo(wb.x) + bflo(wb.z));
        yo.y = fmaxf(0.f, (x.y - mu) * rs * bfhi(wb.x) + bfhi(wb.z));
        yo.z = fmaxf(0.f, (x.z - mu) * rs * bflo(wb.y) + bflo(wb.w));
        yo.w = fmaxf(0.f, (x.w - mu) * rs * bfhi(wb.y) + bfhi(wb.w));
        lout4[i] = yo;
        ushort4 ys;
        ys.x = f2bf(yo.x); ys.y = f2bf(yo.y); ys.z = f2bf(yo.z); ys.w = f2bf(yo.w);
        sy16[i] = ys;                          // own slot, no race
    }
    __syncthreads();

    // ---- phase 2: cat GEMVs from LDS, float4 Wcat (cq = t&3, fg = t>>2) ----
    const int cq = t & 3;
    const int fg = t >> 2;                    // 0..63
    for (int k = 0; k < N_CAT; ++k) {
        const float4* Wc4 = (const float4*)(Wcat + (size_t)k * F_DIM * CAT_D);
        float4 a4 = {0.f, 0.f, 0.f, 0.f};
#pragma unroll
        for (int jq = 0; jq < 4; ++jq) {
            ushort4 yv = sy16[(k << 8) + fg * 4 + jq];
            float ys[4] = {bf2f(yv.x), bf2f(yv.y), bf2f(yv.z), bf2f(yv.w)};
#pragma unroll
            for (int r = 0; r < 4; ++r) {
                int f = fg * 16 + jq * 4 + r;
                float4 wv = Wc4[f * 4 + cq];
                a4.x += ys[r] * wv.x;
                a4.y += ys[r] * wv.y;
                a4.z += ys[r] * wv.z;
                a4.w += ys[r] * wv.w;
            }
        }
#pragma unroll
        for (int o = 4; o < 64; o <<= 1) {
            a4.x += __shfl_xor(a4.x, o);
            a4.y += __shfl_xor(a4.y, o);
            a4.z += __shfl_xor(a4.z, o);
            a4.w += __shfl_xor(a4.w, o);
        }
        if (lane < 4) cred4[w4][k][lane] = a4;   // lane == cq for lanes 0..3
    }
    __syncthreads();

    // ---- phase 3: softmax ----
    if (t < 128) {                            // h = t>>4, c = t&15
        const int h = t >> 4, c = t & 15;
        float lg = bcat[h * CAT_D + c];
#pragma unroll
        for (int w = 0; w < 4; ++w)
            lg += ((const float*)cred4[w][h])[c];
        float mx = lg;
#pragma unroll
        for (int o = 8; o; o >>= 1) mx = fmaxf(mx, __shfl_xor(mx, o, 16));
        float e = __expf(lg - mx);
        float sm2 = e;
#pragma unroll
        for (int o = 8; o; o >>= 1) sm2 += __shfl_xor(sm2, o, 16);
        pcat[(size_t)b * (N_CAT * CAT_D) + t] = e / sm2;
    }
}

extern "C" void kernel_launch(void* const* d_in, const int* in_sizes, int n_in,
                              void* d_out, int out_size, void* d_ws, size_t ws_size,
                              hipStream_t stream) {
    const float* z     = (const float*)d_in[0];
    // d_in[1] = edge (unused by reference computation)
    const float* Wp    = (const float*)d_in[2];
    const float* bp    = (const float*)d_in[3];
    const float* lnw   = (const float*)d_in[4];
    const float* lnb   = (const float*)d_in[5];
    const float* Wcat  = (const float*)d_in[6];
    const float* bcat  = (const float*)d_in[7];
    const float* Wcont = (const float*)d_in[8];
    const float* bcont = (const float*)d_in[9];

    float* out    = (float*)d_out;
    float* pcat   = out;                                   // [4096, 8, 16]
    float* pcont  = out + (size_t)B_SZ * N_CAT * CAT_D;    // [4096, 24, 1]
    float* latent = pcont + (size_t)B_SZ * N_CONT;         // [4096, 32, 1024]

    u16* zb     = (u16*)d_ws;                              // 8 MB
    u16* Wt     = zb + (size_t)B_SZ * F_DIM;               // 64 MB
    float* murs = (float*)(Wt + (size_t)NTOT * F_DIM);     // 32 KB
    float* psum   = murs + 2 * B_SZ;                       // [128][4096] 2 MB
    float* psumsq = psum + (size_t)B_SZ * NSTRIP;          // 2 MB
    uint4* lnwb = (uint4*)(psumsq + (size_t)B_SZ * NSTRIP);        // 128 KB
    ushort4* wc16 = (ushort4*)(lnwb + NTOT / 4);                   // 48 KB
    u16* lat16  = (u16*)(wc16 + N_CONT * F_DIM / 4);       // 256 MB (optional)

    const size_t need = (size_t)((char*)(lat16 + (size_t)B_SZ * NTOT) - (char*)d_ws);
    const bool usebf = ws_size >= need;

    const int LDSB = 131072;
    zconv<<<dim3(B_SZ * F_DIM / 1024), 256, 0, stream>>>(z, zb);
    packln<<<dim3((NTOT / 4 + N_CONT * F_DIM / 4 + 255) / 256), 256, 0, stream>>>(
        lnw, lnb, Wcont, lnwb, wc16);
    transpose_w<<<dim3(16, 16, 32), 256, 0, stream>>>(Wp, Wt);
    if (usebf) {
        (void)hipFuncSetAttribute((const void*)gemm256<1>,
                                  hipFuncAttributeMaxDynamicSharedMemorySize, LDSB);
        gemm256<1><<<dim3(2048), 512, LDSB, stream>>>(zb, Wt, bp, lat16, nullptr,
                                                      psum, psumsq);
        ln_finalize<<<dim3(B_SZ / 64), 256, 0, stream>>>(psum, psumsq, murs);
        contK<1><<<dim3(3, B_SZ), 256, 0, stream>>>(lat16, latent, murs, lnwb, wc16,
                                                    bcont, pcont);
        catK<1><<<dim3(B_SZ), 256, 0, stream>>>(lat16, latent, murs, lnwb,
                                                Wcat, bcat, pcat);
    } else {
        (void)hipFuncSetAttribute((const void*)gemm256<0>,
                                  hipFuncAttributeMaxDynamicSharedMemorySize, LDSB);
        gemm256<0><<<dim3(2048), 512, LDSB, stream>>>(zb, Wt, bp, nullptr, latent,
                                                      psum, psumsq);
        ln_finalize<<<dim3(B_SZ / 64), 256, 0, stream>>>(psum, psumsq, murs);
        contK<0><<<dim3(3, B_SZ), 256, 0, stream>>>(latent, latent, murs, lnwb, wc16,
                                                    bcont, pcont);
        catK<0><<<dim3(B_SZ), 256, 0, stream>>>(latent, latent, murs, lnwb,
                                                Wcat, bcat, pcat);
    }
}